// Round 14
// baseline (619.061 us; speedup 1.0000x reference)
//
#include <hip/hip_runtime.h>
#include <hip/hip_bf16.h>

// Problem constants (match reference)
static constexpr int N_NODES  = 100000;
static constexpr int N_EDGES  = 400000;
static constexpr int DRUG_DIM = 75;
static constexpr int OUT_C    = 256;   // OUT
static constexpr int N_GRAPH  = 2048;  // G
static constexpr int B_CL     = 2048;  // B
static constexpr int CLINE_DIM= 954;

using bf16 = __hip_bfloat16;
using short8 = __attribute__((ext_vector_type(8))) short;
using f32x4  = __attribute__((ext_vector_type(4))) float;

template<class A, class B> struct is_same_t { static constexpr bool v = false; };
template<class A> struct is_same_t<A, A>   { static constexpr bool v = true;  };

// ---------- load/store helpers ----------
__device__ __forceinline__ float ldf(const float* p) { return *p; }
__device__ __forceinline__ float ldf(const bf16* p)  { return __bfloat162float(*p); }
__device__ __forceinline__ void  stf(float* p, float v) { *p = v; }
__device__ __forceinline__ void  stf(bf16* p, float v)  { *p = __float2bfloat16(v); }
__device__ __forceinline__ float bfu(unsigned short u) { return __uint_as_float(((unsigned)u) << 16); }
__device__ __forceinline__ unsigned short f2bu(float f) {
    bf16 h = __float2bfloat16(f);
    return *reinterpret_cast<unsigned short*>(&h);
}

// async global -> LDS, 16B per lane; LDS dest = uniform base + lane*16
__device__ __forceinline__ void gload_lds16(const void* g, void* l) {
    __builtin_amdgcn_global_load_lds(
        (const __attribute__((address_space(1))) void*)g,
        (__attribute__((address_space(3))) void*)l, 16, 0, 0);
}

// ================= input/weight prep =================
__global__ __launch_bounds__(256)
void convert_a_kernel(const float* __restrict__ A, bf16* __restrict__ Ab,
                      int K, int Kpad, int total)
{
    int idx = blockIdx.x * 256 + threadIdx.x;
    if (idx >= total) return;
    int r = idx / Kpad, k = idx - r * Kpad;
    float f = (k < K) ? A[(size_t)r * K + k] : 0.f;
    Ab[idx] = __float2bfloat16(f);
}

// all weight transposes in one launch; NW is always 256
struct WtJob  { const float* W; bf16* Wt; int K; int n0; int Kpad; };
struct WtJobs { WtJob j[8]; };
__global__ __launch_bounds__(256)
void convert_wt8_kernel(WtJobs jobs)
{
    WtJob jb = jobs.j[blockIdx.y];
    int n = blockIdx.x;
    for (int k = threadIdx.x; k < jb.Kpad; k += 256) {
        float f = (k < jb.K) ? jb.W[(size_t)k * 256 + n] : 0.f;
        jb.Wt[(size_t)(jb.n0 + n) * jb.Kpad + k] = __float2bfloat16(f);
    }
}

__global__ __launch_bounds__(256)
void concat3_kernel(const float* __restrict__ a, const float* __restrict__ b,
                    const float* __restrict__ c, float* __restrict__ out)
{
    int i = blockIdx.x * 256 + threadIdx.x;
    if (i < 256)      out[i] = a[i];
    else if (i < 512) out[i] = b[i - 256];
    else if (i < 768) out[i] = c[i - 512];
}

// ================= MFMA GEMM: 64x256 tile, BK=32 dbuf, COUNTED vmcnt =========
// XCD-aware bijective block swizzle (8 XCDs, m204): each XCD gets a contiguous
// wgid range, ntile fastest -> A-tile siblings share one XCD L2.
// Plane-split output: slab [ntile*256,+256) -> C + ntile*PS + row*256 + col.
// A bf16 [M][K], K mult of 64. Tile 64x256, 4 waves (1x4 col slabs), 40KB LDS.
// LDS relation per 32-elem row: LDS[row][chunk16B] = data[row][chunk ^ ((row>>1)&3)]
// via pre-swizzled GLOBAL source (LDS dest linear). Out-of-range A rows are
// CLAMPED to M-1 (not skipped) so every wave issues exactly 5 loads/stage ->
// constant vmcnt(5); garbage rows are row-independent in MFMA and masked at store.
// Sync (catalog T4): stage(next) -> s_waitcnt vmcnt(5) (current buffer's loads
// done, next's 5 stay IN FLIGHT across the barrier) -> s_barrier -> MFMA -> s_barrier.
template<int ACT, typename TO>
__global__ __launch_bounds__(256)
void mfma_gemm_kernel(const bf16* __restrict__ A, const bf16* __restrict__ Wt,
                      const float* __restrict__ bias, const bf16* __restrict__ res,
                      TO* __restrict__ C, int M, int K, size_t PS,
                      int NTILES, int nwg)
{
    __shared__ alignas(16) short As2[2][64 * 32];    // 2 x 4 KB
    __shared__ alignas(16) short Bs2[2][256 * 32];   // 2 x 16 KB

    // bijective XCD swizzle
    const int id  = blockIdx.x;
    const int qq  = nwg >> 3, rr = nwg & 7;
    const int xcd = id & 7, loc = id >> 3;
    const int wgid = (xcd < rr ? xcd * (qq + 1) : rr * (qq + 1) + (xcd - rr) * qq) + loc;
    const int ntile = wgid % NTILES, mtile = wgid / NTILES;

    const int tid = threadIdx.x;
    const int lane = tid & 63, wid = tid >> 6;   // wave col = wid (0..3)

    f32x4 acc[4][4] = {};

    // staging: 20 issues of 1KB (A: 4, B: 16), 5 per wave; each = 16 rows x 64B
    const int l4 = lane >> 2;                            // row-in-issue (0..15)
    const int schunk = (lane & 3) ^ ((lane >> 3) & 3);   // pre-swizzled src 16B-chunk
    auto stage = [&](int b, int k0) {
        #pragma unroll
        for (int i = 0; i < 5; ++i) {
            const int ci = wid * 5 + i;            // wave-uniform 0..19
            if (ci < 4) {
                int grow = mtile * 64 + ci * 16 + l4;
                if (grow >= M) grow = M - 1;       // clamp: keep issue count constant
                gload_lds16(A + (size_t)grow * K + k0 + schunk * 8,
                            &As2[b][ci * 512]);
            } else {
                const int cb  = ci - 4;
                const int row = cb * 16 + l4;
                gload_lds16(Wt + (size_t)(ntile * 256 + row) * K + k0 + schunk * 8,
                            &Bs2[b][cb * 512]);
            }
        }
    };

    const int NT = K >> 5;
    stage(0, 0);

    for (int t = 0; t < NT; ++t) {
        const int cur = t & 1;
        if (t + 1 < NT) {
            stage(cur ^ 1, (t + 1) << 5);                       // overlaps: stays in flight
            asm volatile("s_waitcnt vmcnt(5)" ::: "memory");    // cur's 5 loads landed
        } else {
            asm volatile("s_waitcnt vmcnt(0)" ::: "memory");
        }
        __builtin_amdgcn_s_barrier();          // all waves' cur portions landed
        __builtin_amdgcn_sched_barrier(0);     // pin LDS reads after the barrier
        // compute buf[cur]: read swizzle chunk' = c ^ ((row>>1)&3), c = lane>>4
        const int coff = (((lane >> 4) ^ ((lane >> 1) & 3))) << 3;
        short8 a[4], b[4];
        #pragma unroll
        for (int m = 0; m < 4; ++m)
            a[m] = *reinterpret_cast<const short8*>(
                &As2[cur][(m * 16 + (lane & 15)) * 32 + coff]);
        #pragma unroll
        for (int n = 0; n < 4; ++n)
            b[n] = *reinterpret_cast<const short8*>(
                &Bs2[cur][(wid * 64 + n * 16 + (lane & 15)) * 32 + coff]);
        #pragma unroll
        for (int m = 0; m < 4; ++m)
            #pragma unroll
            for (int n = 0; n < 4; ++n)
                acc[m][n] = __builtin_amdgcn_mfma_f32_16x16x32_bf16(
                    a[m], b[n], acc[m][n], 0, 0, 0);
        __builtin_amdgcn_sched_barrier(0);     // keep reads before the barrier below
        if (t + 1 < NT) __builtin_amdgcn_s_barrier();  // cur reads done -> next overwrite ok
    }

    // epilogue: C/D layout col=lane&15, row=(lane>>4)*4+reg
    TO* Cp = C + (size_t)ntile * PS;   // plane base
    if constexpr (is_same_t<TO, bf16>::v) {
        // per-wave private 8KB bounce region spanning Bs2 (wave-private reads only)
        short* eb = (short*)Bs2 + wid * 4096;
        #pragma unroll
        for (int m = 0; m < 4; ++m)
            #pragma unroll
            for (int n = 0; n < 4; ++n) {
                int col_l = n * 16 + (lane & 15);
                float bcol = bias[ntile * 256 + wid * 64 + col_l];
                #pragma unroll
                for (int r = 0; r < 4; ++r) {
                    int row_l = m * 16 + ((lane >> 4) << 2) + r;
                    float val = acc[m][n][r] + bcol;
                    if (ACT == 1) val = tanhf(val);
                    if (ACT == 2) val = fmaxf(val, 0.f);
                    eb[row_l * 64 + (col_l ^ ((row_l & 7) << 3))] = (short)f2bu(val);
                }
            }
        // read back coalesced: 8 lanes per row, 16B per lane (wave-private)
        #pragma unroll
        for (int i = 0; i < 8; ++i) {
            int row_l = i * 8 + (lane >> 3);
            int row_g = mtile * 64 + row_l;
            short8 vr = *reinterpret_cast<const short8*>(
                &eb[row_l * 64 + ((((lane & 7) << 3)) ^ ((row_l & 7) << 3))]);
            if (row_g < M)
                *reinterpret_cast<short8*>(
                    &Cp[(size_t)row_g * 256 + wid * 64 + ((lane & 7) << 3)]) = vr;
        }
    } else {
        #pragma unroll
        for (int m = 0; m < 4; ++m) {
            int row0 = mtile * 64 + m * 16 + ((lane >> 4) << 2);
            #pragma unroll
            for (int n = 0; n < 4; ++n) {
                int col_l = wid * 64 + n * 16 + (lane & 15);
                float bcol = bias[ntile * 256 + col_l];
                #pragma unroll
                for (int r = 0; r < 4; ++r) {
                    int row = row0 + r;
                    if (row < M) {
                        float val = acc[m][n][r] + bcol;
                        if (ACT == 1) val = tanhf(val);
                        if (ACT == 2) val = fmaxf(val, 0.f);
                        if (res) val += ldf(&res[(size_t)row * 256 + col_l]);
                        stf(&Cp[(size_t)row * 256 + col_l], val);
                    }
                }
            }
        }
    }
}

// ================= CSR build =================
__global__ __launch_bounds__(256)
void hist_kernel(const int* __restrict__ dst, int* __restrict__ deg, int E)
{
    int e = blockIdx.x * 256 + threadIdx.x;
    if (e < E) atomicAdd(&deg[dst[e]], 1);
}

__global__ __launch_bounds__(256)
void scan1_kernel(const int* __restrict__ deg, int* __restrict__ part,
                  int* __restrict__ bsum, int n)
{
    __shared__ int sh[256];
    const int t = threadIdx.x;
    const int b0 = blockIdx.x * 1024;
    int v[4]; int s = 0;
    #pragma unroll
    for (int j = 0; j < 4; ++j) {
        int idx = b0 + t * 4 + j;
        v[j] = (idx < n) ? deg[idx] : 0;
        s += v[j];
    }
    sh[t] = s; __syncthreads();
    for (int off = 1; off < 256; off <<= 1) {
        int x = (t >= off) ? sh[t - off] : 0;
        __syncthreads();
        sh[t] += x;
        __syncthreads();
    }
    if (t == 255) bsum[blockIdx.x] = sh[255];
    int run = sh[t] - s;
    #pragma unroll
    for (int j = 0; j < 4; ++j) {
        int idx = b0 + t * 4 + j;
        if (idx < n) part[idx] = run;
        run += v[j];
    }
}

__global__ __launch_bounds__(256)
void scan2_kernel(const int* __restrict__ bsum, int* __restrict__ bsume, int nb)
{
    __shared__ int sh[256];
    const int t = threadIdx.x;
    int x0 = (t < nb) ? bsum[t] : 0;
    sh[t] = x0; __syncthreads();
    for (int off = 1; off < 256; off <<= 1) {
        int x = (t >= off) ? sh[t - off] : 0;
        __syncthreads();
        sh[t] += x;
        __syncthreads();
    }
    if (t < nb) bsume[t] = sh[t] - x0;
}

__global__ __launch_bounds__(256)
void scan3_kernel(int* __restrict__ rowptr, int* __restrict__ cursor,
                  const int* __restrict__ bsume, int n, int E)
{
    int idx = blockIdx.x * 256 + threadIdx.x;
    if (idx < n) {
        int val = rowptr[idx] + bsume[idx >> 10];
        rowptr[idx] = val;
        cursor[idx] = val;
    }
    if (idx == 0) rowptr[n] = E;
}

__global__ __launch_bounds__(256)
void scatter_kernel(const int* __restrict__ src, const int* __restrict__ dst,
                    int* __restrict__ cursor, int* __restrict__ esrc, int E)
{
    int e = blockIdx.x * 256 + threadIdx.x;
    if (e < E) {
        int slot = atomicAdd(&cursor[dst[e]], 1);
        esrc[slot] = src[e];
    }
}

// ================= fused flash-style attention (CSR gather, planes) ==========
// wave per dst node. q/k/v: compact [N,256] planes. out: [N,256] (out may == q).
// 2-edge unroll + branchy rescale (numerically identical to always-rescale).
__global__ __launch_bounds__(256)
void attn_fused_kernel(const int* __restrict__ rowptr, const int* __restrict__ esrc,
                       const bf16* __restrict__ q, const bf16* __restrict__ k,
                       const bf16* __restrict__ v, bf16* __restrict__ out, int n)
{
    int node = blockIdx.x * 4 + (threadIdx.x >> 6);
    if (node >= n) return;
    int lane = threadIdx.x & 63;
    int lo = rowptr[node], hi = rowptr[node + 1];

    ushort4 qu = ((const ushort4*)(q + (size_t)node * 256))[lane];
    float q0 = bfu(qu.x), q1 = bfu(qu.y), q2 = bfu(qu.z), q3 = bfu(qu.w);

    float m = -INFINITY, s = 0.f;
    float a0 = 0.f, a1 = 0.f, a2 = 0.f, a3 = 0.f;

    auto upd = [&](float l, ushort4 vu) {
        if (l > m) {
            float sc = __expf(m - l);      // exp(-inf)=0 handles first edge
            a0 *= sc; a1 *= sc; a2 *= sc; a3 *= sc; s *= sc;
            m = l;
        }
        float e = __expf(l - m);
        a0 = fmaf(e, bfu(vu.x), a0);
        a1 = fmaf(e, bfu(vu.y), a1);
        a2 = fmaf(e, bfu(vu.z), a2);
        a3 = fmaf(e, bfu(vu.w), a3);
        s += e;
    };

    int i = lo;
    for (; i + 2 <= hi; i += 2) {
        int sn0 = esrc[i], sn1 = esrc[i + 1];
        ushort4 ku0 = ((const ushort4*)(k + (size_t)sn0 * 256))[lane];
        ushort4 vu0 = ((const ushort4*)(v + (size_t)sn0 * 256))[lane];
        ushort4 ku1 = ((const ushort4*)(k + (size_t)sn1 * 256))[lane];
        ushort4 vu1 = ((const ushort4*)(v + (size_t)sn1 * 256))[lane];
        float p0 = q0 * bfu(ku0.x);
        p0 = fmaf(q1, bfu(ku0.y), p0);
        p0 = fmaf(q2, bfu(ku0.z), p0);
        p0 = fmaf(q3, bfu(ku0.w), p0);
        float p1 = q0 * bfu(ku1.x);
        p1 = fmaf(q1, bfu(ku1.y), p1);
        p1 = fmaf(q2, bfu(ku1.z), p1);
        p1 = fmaf(q3, bfu(ku1.w), p1);
        p0 += __shfl_xor(p0, 1);  p1 += __shfl_xor(p1, 1);
        p0 += __shfl_xor(p0, 2);  p1 += __shfl_xor(p1, 2);
        p0 += __shfl_xor(p0, 4);  p1 += __shfl_xor(p1, 4);
        p0 += __shfl_xor(p0, 8);  p1 += __shfl_xor(p1, 8);
        upd(p0 * 0.125f, vu0);
        upd(p1 * 0.125f, vu1);
    }
    if (i < hi) {
        int sn = esrc[i];
        ushort4 ku = ((const ushort4*)(k + (size_t)sn * 256))[lane];
        ushort4 vu = ((const ushort4*)(v + (size_t)sn * 256))[lane];
        float p = q0 * bfu(ku.x);
        p = fmaf(q1, bfu(ku.y), p);
        p = fmaf(q2, bfu(ku.z), p);
        p = fmaf(q3, bfu(ku.w), p);
        p += __shfl_xor(p, 1);
        p += __shfl_xor(p, 2);
        p += __shfl_xor(p, 4);
        p += __shfl_xor(p, 8);
        upd(p * 0.125f, vu);
    }

    float inv = 1.f / (s + 1e-16f);
    ushort4 o;
    o.x = f2bu(fmaxf(a0 * inv, 0.f));
    o.y = f2bu(fmaxf(a1 * inv, 0.f));
    o.z = f2bu(fmaxf(a2 * inv, 0.f));
    o.w = f2bu(fmaxf(a3 * inv, 0.f));
    ((ushort4*)(out + (size_t)node * 256))[lane] = o;
}

// ---------- per-channel BN stats (compact [M,256]) ----------
template<typename TX>
__global__ __launch_bounds__(256)
void col_stats_kernel(const TX* __restrict__ x, float* __restrict__ bnsum,
                      float* __restrict__ bnsumsq, int M)
{
    const int c = threadIdx.x;
    const int r0 = blockIdx.x * 64;
    const int r1 = min(r0 + 64, M);
    float ls = 0.f, lq = 0.f;
    for (int r = r0; r < r1; ++r) {
        float val = ldf(&x[(size_t)r * 256 + c]);
        ls += val;
        lq += val * val;
    }
    atomicAdd(&bnsum[c], ls);
    atomicAdd(&bnsumsq[c], lq);
}

// ---------- BN fold into following weights ----------
__global__ __launch_bounds__(256)
void bn_fold_kernel(bf16* __restrict__ Wt, const float* __restrict__ bin,
                    float* __restrict__ bout,
                    const float* __restrict__ bnsum, const float* __restrict__ bnsumsq,
                    const float* __restrict__ g, const float* __restrict__ be,
                    float* __restrict__ s_out, float* __restrict__ t_out, float invM)
{
    __shared__ float sh[256];
    const int n = blockIdx.x, k = threadIdx.x;
    float mu  = bnsum[k] * invM;
    float var = bnsumsq[k] * invM - mu * mu;
    float scale = g[k] * rsqrtf(var + 1e-5f);
    float shift = be[k] - mu * scale;
    float w = ldf(&Wt[(size_t)n * 256 + k]);
    Wt[(size_t)n * 256 + k] = __float2bfloat16(w * scale);
    sh[k] = shift * w;
    __syncthreads();
    for (int off = 128; off; off >>= 1) {
        if (k < off) sh[k] += sh[k + off];
        __syncthreads();
    }
    if (k == 0) bout[n] = bin[n] + sh[0];
    if (s_out && n == 0) { s_out[k] = scale; t_out[k] = shift; }
}

// ---------- fused bn2 + residual + segment-mean pool ----------
__global__ __launch_bounds__(256)
void pool_bn_kernel(const bf16* __restrict__ a2, const bf16* __restrict__ h1,
                    const int* __restrict__ ibatch,
                    const float* __restrict__ bnsum, const float* __restrict__ bnsumsq,
                    const float* __restrict__ g2, const float* __restrict__ be2,
                    const float* __restrict__ s1, const float* __restrict__ t1,
                    float* __restrict__ out, float invM)
{
    int g = blockIdx.x;
    __shared__ int bounds[2];
    if (threadIdx.x == 0) {
        int lo = 0, hi = N_NODES;
        while (lo < hi) { int mid = (lo + hi) >> 1; if (ibatch[mid] < g) lo = mid + 1; else hi = mid; }
        bounds[0] = lo;
        int lo2 = lo, hi2 = N_NODES;
        while (lo2 < hi2) { int mid = (lo2 + hi2) >> 1; if (ibatch[mid] < g + 1) lo2 = mid + 1; else hi2 = mid; }
        bounds[1] = lo2;
    }
    __syncthreads();
    int lo = bounds[0], hi = bounds[1];
    int c = threadIdx.x;
    float sa = 0.f, sh = 0.f;
    for (int r = lo; r < hi; ++r) {
        sa += ldf(&a2[(size_t)r * 256 + c]);
        sh += ldf(&h1[(size_t)r * 256 + c]);
    }
    float mu  = bnsum[c] * invM;
    float var = bnsumsq[c] * invM - mu * mu;
    float sc2 = g2[c] * rsqrtf(var + 1e-5f);
    float sh2 = be2[c] - mu * sc2;
    int cnt = hi - lo;
    out[(size_t)g * 256 + c] =
        (cnt > 0) ? (sc2 * sa + s1[c] * sh) / cnt + sh2 + t1[c] : 0.f;
}

extern "C" void kernel_launch(void* const* d_in, const int* in_sizes, int n_in,
                              void* d_out, int out_size, void* d_ws, size_t ws_size,
                              hipStream_t stream)
{
    const float* drug_x  = (const float*)d_in[0];
    const int*   adj     = (const int*)  d_in[1];
    const int*   ibatch  = (const int*)  d_in[2];
    const float* cline_x = (const float*)d_in[3];
    const float* Wq1 = (const float*)d_in[4];  const float* bq1 = (const float*)d_in[5];
    const float* Wk1 = (const float*)d_in[6];  const float* bk1 = (const float*)d_in[7];
    const float* Wv1 = (const float*)d_in[8];  const float* bv1 = (const float*)d_in[9];
    const float* g1  = (const float*)d_in[10]; const float* be1 = (const float*)d_in[11];
    const float* Wq2 = (const float*)d_in[12]; const float* bq2 = (const float*)d_in[13];
    const float* Wk2 = (const float*)d_in[14]; const float* bk2 = (const float*)d_in[15];
    const float* Wv2 = (const float*)d_in[16]; const float* bv2 = (const float*)d_in[17];
    const float* g2  = (const float*)d_in[18]; const float* be2 = (const float*)d_in[19];
    const float* Wc1 = (const float*)d_in[20]; const float* bc1 = (const float*)d_in[21];
    const float* gc  = (const float*)d_in[22]; const float* bec = (const float*)d_in[23];
    const float* Wc2 = (const float*)d_in[24]; const float* bc2 = (const float*)d_in[25];

    const int* srcp = adj;
    const int* dstp = adj + N_EDGES;

    // ---- workspace arena (~209 MB) ----
    char* p = (char*)d_ws;
    auto take = [&p](size_t bytes) {
        char* r = p;
        p += (bytes + 15) & ~(size_t)15;
        return r;
    };
    const size_t PS = (size_t)N_NODES * 256;   // plane stride (elements)
    bf16*  qkv   = (bf16*)take(PS * 3 * sizeof(bf16));   // planes q|k|v; attn2 out in q-plane
    bf16*  h1    = (bf16*)take(PS * sizeof(bf16));       // drug_xb -> attnout1
    int*   rowptr= (int*)take((size_t)(N_NODES + 1) * sizeof(int));
    int*   degcur= (int*)take((size_t)N_NODES * sizeof(int));
    int*   bsum  = (int*)take(256 * sizeof(int));
    int*   bsume = (int*)take(256 * sizeof(int));
    int*   esrc  = (int*)take((size_t)N_EDGES * sizeof(int));
    float* bnsum = (float*)take(256 * sizeof(float));
    float* bnsumsq=(float*)take(256 * sizeof(float));
    float* s1buf = (float*)take(256 * sizeof(float));
    float* t1buf = (float*)take(256 * sizeof(float));
    bf16*  Wt1   = (bf16*)take((size_t)768 * 128 * sizeof(bf16));
    bf16*  Wt2   = (bf16*)take((size_t)768 * 256 * sizeof(bf16));
    bf16*  Wtc1  = (bf16*)take((size_t)256 * 960 * sizeof(bf16));
    bf16*  Wtc2  = (bf16*)take((size_t)256 * 256 * sizeof(bf16));
    float* bc2f  = (float*)take(256 * sizeof(float));
    float* bias1 = (float*)take(768 * sizeof(float));
    float* bias2 = (float*)take(768 * sizeof(float));
    size_t needed = (size_t)(p - (char*)d_ws);
    if (ws_size < needed) return;

    // aliases (lifetime-disjoint):
    bf16* drug_xb  = h1;                       // [N,128] bf16, dead before L1 attn writes
    bf16* cline_xb = qkv;                      // [2048,960] bf16 (qkv dead after pool)
    bf16* c1b      = qkv + (size_t)2048 * 960; // [2048,256] bf16 tanh output

    bf16* qpl = qkv;            // q plane
    bf16* kpl = qkv + PS;       // k plane
    bf16* vpl = qkv + 2 * PS;   // v plane

    float* out_pool = (float*)d_out;                      // [G,256]
    float* out_c    = out_pool + (size_t)N_GRAPH * OUT_C; // [B,256]

    const int MT_N = (N_NODES + 63) / 64;    // 1563 mtiles
    const int nwgN = 3 * MT_N;               // drug GEMM: ntile fastest in wgid
    const int nwgB = B_CL / 64;              // 32 (NTILES=1)
    const int nodeBlocks = (N_NODES + 3) / 4;

    // ===================== prep =====================
    convert_a_kernel<<<(N_NODES * 128 + 255) / 256, 256, 0, stream>>>(
        drug_x, drug_xb, DRUG_DIM, 128, N_NODES * 128);
    WtJobs jobs = {{
        { Wq1, Wt1, DRUG_DIM,   0, 128 },
        { Wk1, Wt1, DRUG_DIM, 256, 128 },
        { Wv1, Wt1, DRUG_DIM, 512, 128 },
        { Wq2, Wt2, 256,        0, 256 },
        { Wk2, Wt2, 256,      256, 256 },
        { Wv2, Wt2, 256,      512, 256 },
        { Wc1, Wtc1, CLINE_DIM, 0, 960 },
        { Wc2, Wtc2, 256,       0, 256 },
    }};
    convert_wt8_kernel<<<dim3(256, 8), 256, 0, stream>>>(jobs);
    concat3_kernel<<<3, 256, 0, stream>>>(bq1, bk1, bv1, bias1);
    concat3_kernel<<<3, 256, 0, stream>>>(bq2, bk2, bv2, bias2);

    // ===================== CSR build =====================
    hipMemsetAsync(degcur, 0, N_NODES * sizeof(int), stream);
    hist_kernel<<<(N_EDGES + 255) / 256, 256, 0, stream>>>(dstp, degcur, N_EDGES);
    const int NB1 = (N_NODES + 1023) / 1024;
    scan1_kernel<<<NB1, 256, 0, stream>>>(degcur, rowptr, bsum, N_NODES);
    scan2_kernel<<<1, 256, 0, stream>>>(bsum, bsume, NB1);
    scan3_kernel<<<(N_NODES + 255) / 256, 256, 0, stream>>>(rowptr, degcur, bsume, N_NODES, N_EDGES);
    scatter_kernel<<<(N_EDGES + 255) / 256, 256, 0, stream>>>(srcp, dstp, degcur, esrc, N_EDGES);

    // ===================== drug layer 1 =====================
    mfma_gemm_kernel<0, bf16><<<nwgN, 256, 0, stream>>>(
        drug_xb, Wt1, bias1, nullptr, qkv, N_NODES, 128, PS, 3, nwgN);
    // attnout1 (relu'd) -> compact [N,256] into h1 slot (drug_xb dead now)
    attn_fused_kernel<<<nodeBlocks, 256, 0, stream>>>(rowptr, esrc, qpl, kpl, vpl, h1, N_NODES);
    hipMemsetAsync(bnsum, 0, 512 * sizeof(float), stream);
    col_stats_kernel<bf16><<<(N_NODES + 63) / 64, 256, 0, stream>>>(h1, bnsum, bnsumsq, N_NODES);
    // fold BN1 into Wt2/bias2 (in place), export s1/t1 for the residual path
    bn_fold_kernel<<<768, 256, 0, stream>>>(Wt2, bias2, bias2, bnsum, bnsumsq,
                                            g1, be1, s1buf, t1buf, 1.0f / N_NODES);

    // ===================== drug layer 2 =====================
    mfma_gemm_kernel<0, bf16><<<nwgN, 256, 0, stream>>>(
        h1, Wt2, bias2, nullptr, qkv, N_NODES, 256, PS, 3, nwgN);
    // attnout2 -> in-place q-plane (compact)
    attn_fused_kernel<<<nodeBlocks, 256, 0, stream>>>(rowptr, esrc, qpl, kpl, vpl, qpl, N_NODES);
    hipMemsetAsync(bnsum, 0, 512 * sizeof(float), stream);
    col_stats_kernel<bf16><<<(N_NODES + 63) / 64, 256, 0, stream>>>(qpl, bnsum, bnsumsq, N_NODES);
    // fused: pooled = sc2*mean(attnout2) + s1*mean(attnout1) + sh2 + t1
    pool_bn_kernel<<<N_GRAPH, 256, 0, stream>>>(qpl, h1, ibatch, bnsum, bnsumsq,
                                                g2, be2, s1buf, t1buf, out_pool,
                                                1.0f / N_NODES);

    // ===================== cline branch (qkv region now dead) =====================
    convert_a_kernel<<<(B_CL * 960 + 255) / 256, 256, 0, stream>>>(
        cline_x, cline_xb, CLINE_DIM, 960, B_CL * 960);
    mfma_gemm_kernel<1, bf16><<<nwgB, 256, 0, stream>>>(
        cline_xb, Wtc1, bc1, nullptr, c1b, B_CL, 960, 0, 1, nwgB);  // tanh, bf16
    hipMemsetAsync(bnsum, 0, 512 * sizeof(float), stream);
    col_stats_kernel<bf16><<<(B_CL + 63) / 64, 256, 0, stream>>>(c1b, bnsum, bnsumsq, B_CL);
    bn_fold_kernel<<<256, 256, 0, stream>>>(Wtc2, bc2, bc2f, bnsum, bnsumsq,
                                            gc, bec, nullptr, nullptr, 1.0f / B_CL);
    // out_c = c1 + relu(c1 @ Wc2f^T + bc2f)
    mfma_gemm_kernel<2, float><<<nwgB, 256, 0, stream>>>(
        c1b, Wtc2, bc2f, c1b, out_c, B_CL, 256, 0, 1, nwgB);
}

// Round 15
// 600.233 us; speedup vs baseline: 1.0314x; 1.0314x over previous
//
#include <hip/hip_runtime.h>
#include <hip/hip_bf16.h>

// Problem constants (match reference)
static constexpr int N_NODES  = 100000;
static constexpr int N_EDGES  = 400000;
static constexpr int DRUG_DIM = 75;
static constexpr int OUT_C    = 256;   // OUT
static constexpr int N_GRAPH  = 2048;  // G
static constexpr int B_CL     = 2048;  // B
static constexpr int CLINE_DIM= 954;

using bf16 = __hip_bfloat16;
using short8 = __attribute__((ext_vector_type(8))) short;
using f32x4  = __attribute__((ext_vector_type(4))) float;

template<class A, class B> struct is_same_t { static constexpr bool v = false; };
template<class A> struct is_same_t<A, A>   { static constexpr bool v = true;  };

// ---------- load/store helpers ----------
__device__ __forceinline__ float ldf(const float* p) { return *p; }
__device__ __forceinline__ float ldf(const bf16* p)  { return __bfloat162float(*p); }
__device__ __forceinline__ void  stf(float* p, float v) { *p = v; }
__device__ __forceinline__ void  stf(bf16* p, float v)  { *p = __float2bfloat16(v); }
__device__ __forceinline__ float bfu(unsigned short u) { return __uint_as_float(((unsigned)u) << 16); }
__device__ __forceinline__ unsigned short f2bu(float f) {
    bf16 h = __float2bfloat16(f);
    return *reinterpret_cast<unsigned short*>(&h);
}

// async global -> LDS, 16B per lane; LDS dest = uniform base + lane*16
__device__ __forceinline__ void gload_lds16(const void* g, void* l) {
    __builtin_amdgcn_global_load_lds(
        (const __attribute__((address_space(1))) void*)g,
        (__attribute__((address_space(3))) void*)l, 16, 0, 0);
}

// ================= input/weight prep =================
__global__ __launch_bounds__(256)
void convert_a_kernel(const float* __restrict__ A, bf16* __restrict__ Ab,
                      int K, int Kpad, int total)
{
    int idx = blockIdx.x * 256 + threadIdx.x;
    if (idx >= total) return;
    int r = idx / Kpad, k = idx - r * Kpad;
    float f = (k < K) ? A[(size_t)r * K + k] : 0.f;
    Ab[idx] = __float2bfloat16(f);
}

// all weight transposes in one launch; NW is always 256
struct WtJob  { const float* W; bf16* Wt; int K; int n0; int Kpad; };
struct WtJobs { WtJob j[8]; };
__global__ __launch_bounds__(256)
void convert_wt8_kernel(WtJobs jobs)
{
    WtJob jb = jobs.j[blockIdx.y];
    int n = blockIdx.x;
    for (int k = threadIdx.x; k < jb.Kpad; k += 256) {
        float f = (k < jb.K) ? jb.W[(size_t)k * 256 + n] : 0.f;
        jb.Wt[(size_t)(jb.n0 + n) * jb.Kpad + k] = __float2bfloat16(f);
    }
}

__global__ __launch_bounds__(256)
void concat3_kernel(const float* __restrict__ a, const float* __restrict__ b,
                    const float* __restrict__ c, float* __restrict__ out)
{
    int i = blockIdx.x * 256 + threadIdx.x;
    if (i < 256)      out[i] = a[i];
    else if (i < 512) out[i] = b[i - 256];
    else if (i < 768) out[i] = c[i - 512];
}

// ================= MFMA GEMM (single-buffer global_load_lds, 64x256 tile) =====
// r13-proven core. XCD-aware bijective block swizzle (8 XCDs, m204): each XCD
// gets a contiguous wgid range, ntile fastest -> A-tile siblings share one L2.
// Plane-split output: slab [ntile*256,+256) -> C + ntile*PS + row*256 + col.
// A bf16 [M][K], K mult of 64, M mult of 8. Tile 64x256, BK=64, 4 waves (1x4).
// LDS relation: LDS[row][y] = data[row][y ^ ((row&7)<<3)] via pre-swizzled
// global source element (LDS dest stays linear).
template<int ACT, typename TO>
__global__ __launch_bounds__(256)
void mfma_gemm_kernel(const bf16* __restrict__ A, const bf16* __restrict__ Wt,
                      const float* __restrict__ bias, const bf16* __restrict__ res,
                      TO* __restrict__ C, int M, int K, size_t PS,
                      int NTILES, int nwg)
{
    __shared__ alignas(16) short As[64 * 64];    // 8 KB
    __shared__ alignas(16) short Bs[256 * 64];   // 32 KB

    // bijective XCD swizzle
    const int id  = blockIdx.x;
    const int qq  = nwg >> 3, rr = nwg & 7;
    const int xcd = id & 7, loc = id >> 3;
    const int wgid = (xcd < rr ? xcd * (qq + 1) : rr * (qq + 1) + (xcd - rr) * qq) + loc;
    const int ntile = wgid % NTILES, mtile = wgid / NTILES;

    const int tid = threadIdx.x;
    const int lane = tid & 63, wid = tid >> 6;   // wave col = wid (0..3)

    f32x4 acc[4][4] = {};

    for (int k0 = 0; k0 < K; k0 += 64) {
        // 40 staging issues (A: 8 chunks of 8 rows, B: 32 chunks), 10 per wave
        #pragma unroll
        for (int i = 0; i < 10; ++i) {
            const int ci = wid * 10 + i;               // wave-uniform
            if (ci < 8) {
                const int row = ci * 8 + (lane >> 3);
                const int e   = ((lane & 7) ^ (row & 7)) << 3;
                if (mtile * 64 + ci * 8 + 8 <= M)      // wave-uniform guard (M%8==0)
                    gload_lds16(A + (size_t)(mtile * 64 + row) * K + k0 + e,
                                &As[ci * 512]);
            } else {
                const int cb  = ci - 8;
                const int row = cb * 8 + (lane >> 3);
                const int e   = ((lane & 7) ^ (row & 7)) << 3;
                gload_lds16(Wt + (size_t)(ntile * 256 + row) * K + k0 + e,
                            &Bs[cb * 512]);
            }
        }
        __syncthreads();   // drains vmcnt(0): LDS tiles ready
        #pragma unroll
        for (int kk = 0; kk < 2; ++kk) {
            const int coff = (kk * 32 + (lane >> 4) * 8) ^ ((lane & 7) << 3);
            short8 a[4], b[4];
            #pragma unroll
            for (int m = 0; m < 4; ++m)
                a[m] = *reinterpret_cast<const short8*>(
                    &As[(m * 16 + (lane & 15)) * 64 + coff]);
            #pragma unroll
            for (int n = 0; n < 4; ++n)
                b[n] = *reinterpret_cast<const short8*>(
                    &Bs[(wid * 64 + n * 16 + (lane & 15)) * 64 + coff]);
            #pragma unroll
            for (int m = 0; m < 4; ++m)
                #pragma unroll
                for (int n = 0; n < 4; ++n)
                    acc[m][n] = __builtin_amdgcn_mfma_f32_16x16x32_bf16(
                        a[m], b[n], acc[m][n], 0, 0, 0);
        }
        __syncthreads();
    }

    // epilogue: C/D layout col=lane&15, row=(lane>>4)*4+reg
    TO* Cp = C + (size_t)ntile * PS;   // plane base
    if constexpr (is_same_t<TO, bf16>::v) {
        // per-wave private 8KB bounce region in the (now dead) Bs
        short* eb = Bs + wid * 4096;
        #pragma unroll
        for (int m = 0; m < 4; ++m)
            #pragma unroll
            for (int n = 0; n < 4; ++n) {
                int col_l = n * 16 + (lane & 15);
                float bcol = bias[ntile * 256 + wid * 64 + col_l];
                #pragma unroll
                for (int r = 0; r < 4; ++r) {
                    int row_l = m * 16 + ((lane >> 4) << 2) + r;
                    float val = acc[m][n][r] + bcol;
                    if (ACT == 1) val = tanhf(val);
                    if (ACT == 2) val = fmaxf(val, 0.f);
                    eb[row_l * 64 + (col_l ^ ((row_l & 7) << 3))] = (short)f2bu(val);
                }
            }
        // read back coalesced: 8 lanes per row, 16B per lane (wave-private)
        #pragma unroll
        for (int i = 0; i < 8; ++i) {
            int row_l = i * 8 + (lane >> 3);
            int row_g = mtile * 64 + row_l;
            short8 vr = *reinterpret_cast<const short8*>(
                &eb[row_l * 64 + ((((lane & 7) << 3)) ^ ((row_l & 7) << 3))]);
            if (row_g < M)
                *reinterpret_cast<short8*>(
                    &Cp[(size_t)row_g * 256 + wid * 64 + ((lane & 7) << 3)]) = vr;
        }
    } else {
        #pragma unroll
        for (int m = 0; m < 4; ++m) {
            int row0 = mtile * 64 + m * 16 + ((lane >> 4) << 2);
            #pragma unroll
            for (int n = 0; n < 4; ++n) {
                int col_l = wid * 64 + n * 16 + (lane & 15);
                float bcol = bias[ntile * 256 + col_l];
                #pragma unroll
                for (int r = 0; r < 4; ++r) {
                    int row = row0 + r;
                    if (row < M) {
                        float val = acc[m][n][r] + bcol;
                        if (ACT == 1) val = tanhf(val);
                        if (ACT == 2) val = fmaxf(val, 0.f);
                        if (res) val += ldf(&res[(size_t)row * 256 + col_l]);
                        stf(&Cp[(size_t)row * 256 + col_l], val);
                    }
                }
            }
        }
    }
}

// ================= CSR build =================
__global__ __launch_bounds__(256)
void hist_kernel(const int* __restrict__ dst, int* __restrict__ deg, int E)
{
    int e = blockIdx.x * 256 + threadIdx.x;
    if (e < E) atomicAdd(&deg[dst[e]], 1);
}

__global__ __launch_bounds__(256)
void scan1_kernel(const int* __restrict__ deg, int* __restrict__ part,
                  int* __restrict__ bsum, int n)
{
    __shared__ int sh[256];
    const int t = threadIdx.x;
    const int b0 = blockIdx.x * 1024;
    int v[4]; int s = 0;
    #pragma unroll
    for (int j = 0; j < 4; ++j) {
        int idx = b0 + t * 4 + j;
        v[j] = (idx < n) ? deg[idx] : 0;
        s += v[j];
    }
    sh[t] = s; __syncthreads();
    for (int off = 1; off < 256; off <<= 1) {
        int x = (t >= off) ? sh[t - off] : 0;
        __syncthreads();
        sh[t] += x;
        __syncthreads();
    }
    if (t == 255) bsum[blockIdx.x] = sh[255];
    int run = sh[t] - s;
    #pragma unroll
    for (int j = 0; j < 4; ++j) {
        int idx = b0 + t * 4 + j;
        if (idx < n) part[idx] = run;
        run += v[j];
    }
}

__global__ __launch_bounds__(256)
void scan2_kernel(const int* __restrict__ bsum, int* __restrict__ bsume, int nb)
{
    __shared__ int sh[256];
    const int t = threadIdx.x;
    int x0 = (t < nb) ? bsum[t] : 0;
    sh[t] = x0; __syncthreads();
    for (int off = 1; off < 256; off <<= 1) {
        int x = (t >= off) ? sh[t - off] : 0;
        __syncthreads();
        sh[t] += x;
        __syncthreads();
    }
    if (t < nb) bsume[t] = sh[t] - x0;
}

__global__ __launch_bounds__(256)
void scan3_kernel(int* __restrict__ rowptr, int* __restrict__ cursor,
                  const int* __restrict__ bsume, int n, int E)
{
    int idx = blockIdx.x * 256 + threadIdx.x;
    if (idx < n) {
        int val = rowptr[idx] + bsume[idx >> 10];
        rowptr[idx] = val;
        cursor[idx] = val;
    }
    if (idx == 0) rowptr[n] = E;
}

__global__ __launch_bounds__(256)
void scatter_kernel(const int* __restrict__ src, const int* __restrict__ dst,
                    int* __restrict__ cursor, int* __restrict__ esrc, int E)
{
    int e = blockIdx.x * 256 + threadIdx.x;
    if (e < E) {
        int slot = atomicAdd(&cursor[dst[e]], 1);
        esrc[slot] = src[e];
    }
}

// ================= fused attention + BN column stats (CSR gather, planes) =====
// Grid-stride: 2048 blocks x 4 waves; each wave handles nodes node0+8192*k.
// Lane owns the SAME 4 channels (4*lane..+3) for every node -> per-lane
// register accumulation of sum/sumsq over processed nodes; end-of-kernel
// LDS cross-wave reduce + 512 global atomics/block replaces the separate
// col_stats pass (saves a 51MB read-back per layer).
// 2-edge unroll + branchy rescale (numerically identical to always-rescale).
__global__ __launch_bounds__(256)
void attn_fused_kernel(const int* __restrict__ rowptr, const int* __restrict__ esrc,
                       const bf16* __restrict__ q, const bf16* __restrict__ k,
                       const bf16* __restrict__ v, bf16* __restrict__ out,
                       float* __restrict__ bnsum, float* __restrict__ bnsumsq, int n)
{
    __shared__ float red[8][256];   // [wid]=sum, [wid+4]=sumsq; 8 KB
    const int lane = threadIdx.x & 63;
    const int wid  = threadIdx.x >> 6;

    float cs0 = 0.f, cs1 = 0.f, cs2 = 0.f, cs3 = 0.f;
    float cq0 = 0.f, cq1 = 0.f, cq2 = 0.f, cq3 = 0.f;

    for (int node = blockIdx.x * 4 + wid; node < n; node += 8192) {
        int lo = rowptr[node], hi = rowptr[node + 1];

        ushort4 qu = ((const ushort4*)(q + (size_t)node * 256))[lane];
        float q0 = bfu(qu.x), q1 = bfu(qu.y), q2 = bfu(qu.z), q3 = bfu(qu.w);

        float m = -INFINITY, s = 0.f;
        float a0 = 0.f, a1 = 0.f, a2 = 0.f, a3 = 0.f;

        auto upd = [&](float l, ushort4 vu) {
            if (l > m) {
                float sc = __expf(m - l);      // exp(-inf)=0 handles first edge
                a0 *= sc; a1 *= sc; a2 *= sc; a3 *= sc; s *= sc;
                m = l;
            }
            float e = __expf(l - m);
            a0 = fmaf(e, bfu(vu.x), a0);
            a1 = fmaf(e, bfu(vu.y), a1);
            a2 = fmaf(e, bfu(vu.z), a2);
            a3 = fmaf(e, bfu(vu.w), a3);
            s += e;
        };

        int i = lo;
        for (; i + 2 <= hi; i += 2) {
            int sn0 = esrc[i], sn1 = esrc[i + 1];
            ushort4 ku0 = ((const ushort4*)(k + (size_t)sn0 * 256))[lane];
            ushort4 vu0 = ((const ushort4*)(v + (size_t)sn0 * 256))[lane];
            ushort4 ku1 = ((const ushort4*)(k + (size_t)sn1 * 256))[lane];
            ushort4 vu1 = ((const ushort4*)(v + (size_t)sn1 * 256))[lane];
            float p0 = q0 * bfu(ku0.x);
            p0 = fmaf(q1, bfu(ku0.y), p0);
            p0 = fmaf(q2, bfu(ku0.z), p0);
            p0 = fmaf(q3, bfu(ku0.w), p0);
            float p1 = q0 * bfu(ku1.x);
            p1 = fmaf(q1, bfu(ku1.y), p1);
            p1 = fmaf(q2, bfu(ku1.z), p1);
            p1 = fmaf(q3, bfu(ku1.w), p1);
            p0 += __shfl_xor(p0, 1);  p1 += __shfl_xor(p1, 1);
            p0 += __shfl_xor(p0, 2);  p1 += __shfl_xor(p1, 2);
            p0 += __shfl_xor(p0, 4);  p1 += __shfl_xor(p1, 4);
            p0 += __shfl_xor(p0, 8);  p1 += __shfl_xor(p1, 8);
            upd(p0 * 0.125f, vu0);
            upd(p1 * 0.125f, vu1);
        }
        if (i < hi) {
            int sn = esrc[i];
            ushort4 ku = ((const ushort4*)(k + (size_t)sn * 256))[lane];
            ushort4 vu = ((const ushort4*)(v + (size_t)sn * 256))[lane];
            float p = q0 * bfu(ku.x);
            p = fmaf(q1, bfu(ku.y), p);
            p = fmaf(q2, bfu(ku.z), p);
            p = fmaf(q3, bfu(ku.w), p);
            p += __shfl_xor(p, 1);
            p += __shfl_xor(p, 2);
            p += __shfl_xor(p, 4);
            p += __shfl_xor(p, 8);
            upd(p * 0.125f, vu);
        }

        float inv = 1.f / (s + 1e-16f);
        ushort4 o;
        o.x = f2bu(fmaxf(a0 * inv, 0.f));
        o.y = f2bu(fmaxf(a1 * inv, 0.f));
        o.z = f2bu(fmaxf(a2 * inv, 0.f));
        o.w = f2bu(fmaxf(a3 * inv, 0.f));
        ((ushort4*)(out + (size_t)node * 256))[lane] = o;

        // stats from the bf16-rounded values (bit-identical to a read-back)
        float r0 = bfu(o.x), r1 = bfu(o.y), r2 = bfu(o.z), r3 = bfu(o.w);
        cs0 += r0; cq0 += r0 * r0;
        cs1 += r1; cq1 += r1 * r1;
        cs2 += r2; cq2 += r2 * r2;
        cs3 += r3; cq3 += r3 * r3;
    }

    // cross-wave reduce: lane owns channels 4*lane..4*lane+3
    red[wid][lane * 4 + 0] = cs0;  red[wid + 4][lane * 4 + 0] = cq0;
    red[wid][lane * 4 + 1] = cs1;  red[wid + 4][lane * 4 + 1] = cq1;
    red[wid][lane * 4 + 2] = cs2;  red[wid + 4][lane * 4 + 2] = cq2;
    red[wid][lane * 4 + 3] = cs3;  red[wid + 4][lane * 4 + 3] = cq3;
    __syncthreads();
    int t = threadIdx.x;
    float ssum = red[0][t] + red[1][t] + red[2][t] + red[3][t];
    float sqq  = red[4][t] + red[5][t] + red[6][t] + red[7][t];
    atomicAdd(&bnsum[t], ssum);
    atomicAdd(&bnsumsq[t], sqq);
}

// ---------- per-channel BN stats (compact [M,256]) — cline branch only ----------
template<typename TX>
__global__ __launch_bounds__(256)
void col_stats_kernel(const TX* __restrict__ x, float* __restrict__ bnsum,
                      float* __restrict__ bnsumsq, int M)
{
    const int c = threadIdx.x;
    const int r0 = blockIdx.x * 64;
    const int r1 = min(r0 + 64, M);
    float ls = 0.f, lq = 0.f;
    for (int r = r0; r < r1; ++r) {
        float val = ldf(&x[(size_t)r * 256 + c]);
        ls += val;
        lq += val * val;
    }
    atomicAdd(&bnsum[c], ls);
    atomicAdd(&bnsumsq[c], lq);
}

// ---------- BN fold into following weights ----------
__global__ __launch_bounds__(256)
void bn_fold_kernel(bf16* __restrict__ Wt, const float* __restrict__ bin,
                    float* __restrict__ bout,
                    const float* __restrict__ bnsum, const float* __restrict__ bnsumsq,
                    const float* __restrict__ g, const float* __restrict__ be,
                    float* __restrict__ s_out, float* __restrict__ t_out, float invM)
{
    __shared__ float sh[256];
    const int n = blockIdx.x, k = threadIdx.x;
    float mu  = bnsum[k] * invM;
    float var = bnsumsq[k] * invM - mu * mu;
    float scale = g[k] * rsqrtf(var + 1e-5f);
    float shift = be[k] - mu * scale;
    float w = ldf(&Wt[(size_t)n * 256 + k]);
    Wt[(size_t)n * 256 + k] = __float2bfloat16(w * scale);
    sh[k] = shift * w;
    __syncthreads();
    for (int off = 128; off; off >>= 1) {
        if (k < off) sh[k] += sh[k + off];
        __syncthreads();
    }
    if (k == 0) bout[n] = bin[n] + sh[0];
    if (s_out && n == 0) { s_out[k] = scale; t_out[k] = shift; }
}

// ---------- fused bn2 + residual + segment-mean pool ----------
__global__ __launch_bounds__(256)
void pool_bn_kernel(const bf16* __restrict__ a2, const bf16* __restrict__ h1,
                    const int* __restrict__ ibatch,
                    const float* __restrict__ bnsum, const float* __restrict__ bnsumsq,
                    const float* __restrict__ g2, const float* __restrict__ be2,
                    const float* __restrict__ s1, const float* __restrict__ t1,
                    float* __restrict__ out, float invM)
{
    int g = blockIdx.x;
    __shared__ int bounds[2];
    if (threadIdx.x == 0) {
        int lo = 0, hi = N_NODES;
        while (lo < hi) { int mid = (lo + hi) >> 1; if (ibatch[mid] < g) lo = mid + 1; else hi = mid; }
        bounds[0] = lo;
        int lo2 = lo, hi2 = N_NODES;
        while (lo2 < hi2) { int mid = (lo2 + hi2) >> 1; if (ibatch[mid] < g + 1) lo2 = mid + 1; else hi2 = mid; }
        bounds[1] = lo2;
    }
    __syncthreads();
    int lo = bounds[0], hi = bounds[1];
    int c = threadIdx.x;
    float sa = 0.f, sh = 0.f;
    for (int r = lo; r < hi; ++r) {
        sa += ldf(&a2[(size_t)r * 256 + c]);
        sh += ldf(&h1[(size_t)r * 256 + c]);
    }
    float mu  = bnsum[c] * invM;
    float var = bnsumsq[c] * invM - mu * mu;
    float sc2 = g2[c] * rsqrtf(var + 1e-5f);
    float sh2 = be2[c] - mu * sc2;
    int cnt = hi - lo;
    out[(size_t)g * 256 + c] =
        (cnt > 0) ? (sc2 * sa + s1[c] * sh) / cnt + sh2 + t1[c] : 0.f;
}

extern "C" void kernel_launch(void* const* d_in, const int* in_sizes, int n_in,
                              void* d_out, int out_size, void* d_ws, size_t ws_size,
                              hipStream_t stream)
{
    const float* drug_x  = (const float*)d_in[0];
    const int*   adj     = (const int*)  d_in[1];
    const int*   ibatch  = (const int*)  d_in[2];
    const float* cline_x = (const float*)d_in[3];
    const float* Wq1 = (const float*)d_in[4];  const float* bq1 = (const float*)d_in[5];
    const float* Wk1 = (const float*)d_in[6];  const float* bk1 = (const float*)d_in[7];
    const float* Wv1 = (const float*)d_in[8];  const float* bv1 = (const float*)d_in[9];
    const float* g1  = (const float*)d_in[10]; const float* be1 = (const float*)d_in[11];
    const float* Wq2 = (const float*)d_in[12]; const float* bq2 = (const float*)d_in[13];
    const float* Wk2 = (const float*)d_in[14]; const float* bk2 = (const float*)d_in[15];
    const float* Wv2 = (const float*)d_in[16]; const float* bv2 = (const float*)d_in[17];
    const float* g2  = (const float*)d_in[18]; const float* be2 = (const float*)d_in[19];
    const float* Wc1 = (const float*)d_in[20]; const float* bc1 = (const float*)d_in[21];
    const float* gc  = (const float*)d_in[22]; const float* bec = (const float*)d_in[23];
    const float* Wc2 = (const float*)d_in[24]; const float* bc2 = (const float*)d_in[25];

    const int* srcp = adj;
    const int* dstp = adj + N_EDGES;

    // ---- workspace arena (~209 MB) ----
    char* p = (char*)d_ws;
    auto take = [&p](size_t bytes) {
        char* r = p;
        p += (bytes + 15) & ~(size_t)15;
        return r;
    };
    const size_t PS = (size_t)N_NODES * 256;   // plane stride (elements)
    bf16*  qkv   = (bf16*)take(PS * 3 * sizeof(bf16));   // planes q|k|v; attn2 out in q-plane
    bf16*  h1    = (bf16*)take(PS * sizeof(bf16));       // drug_xb -> attnout1
    int*   rowptr= (int*)take((size_t)(N_NODES + 1) * sizeof(int));
    int*   degcur= (int*)take((size_t)N_NODES * sizeof(int));
    int*   bsum  = (int*)take(256 * sizeof(int));
    int*   bsume = (int*)take(256 * sizeof(int));
    int*   esrc  = (int*)take((size_t)N_EDGES * sizeof(int));
    float* bnsum = (float*)take(256 * sizeof(float));
    float* bnsumsq=(float*)take(256 * sizeof(float));
    float* s1buf = (float*)take(256 * sizeof(float));
    float* t1buf = (float*)take(256 * sizeof(float));
    bf16*  Wt1   = (bf16*)take((size_t)768 * 128 * sizeof(bf16));
    bf16*  Wt2   = (bf16*)take((size_t)768 * 256 * sizeof(bf16));
    bf16*  Wtc1  = (bf16*)take((size_t)256 * 960 * sizeof(bf16));
    bf16*  Wtc2  = (bf16*)take((size_t)256 * 256 * sizeof(bf16));
    float* bc2f  = (float*)take(256 * sizeof(float));
    float* bias1 = (float*)take(768 * sizeof(float));
    float* bias2 = (float*)take(768 * sizeof(float));
    size_t needed = (size_t)(p - (char*)d_ws);
    if (ws_size < needed) return;

    // aliases (lifetime-disjoint):
    bf16* drug_xb  = h1;                       // [N,128] bf16, dead before L1 attn writes
    bf16* cline_xb = qkv;                      // [2048,960] bf16 (qkv dead after pool)
    bf16* c1b      = qkv + (size_t)2048 * 960; // [2048,256] bf16 tanh output

    bf16* qpl = qkv;            // q plane
    bf16* kpl = qkv + PS;       // k plane
    bf16* vpl = qkv + 2 * PS;   // v plane

    float* out_pool = (float*)d_out;                      // [G,256]
    float* out_c    = out_pool + (size_t)N_GRAPH * OUT_C; // [B,256]

    const int MT_N = (N_NODES + 63) / 64;    // 1563 mtiles
    const int nwgN = 3 * MT_N;               // drug GEMM: ntile fastest in wgid
    const int nwgB = B_CL / 64;              // 32 (NTILES=1)

    // ===================== prep =====================
    convert_a_kernel<<<(N_NODES * 128 + 255) / 256, 256, 0, stream>>>(
        drug_x, drug_xb, DRUG_DIM, 128, N_NODES * 128);
    WtJobs jobs = {{
        { Wq1, Wt1, DRUG_DIM,   0, 128 },
        { Wk1, Wt1, DRUG_DIM, 256, 128 },
        { Wv1, Wt1, DRUG_DIM, 512, 128 },
        { Wq2, Wt2, 256,        0, 256 },
        { Wk2, Wt2, 256,      256, 256 },
        { Wv2, Wt2, 256,      512, 256 },
        { Wc1, Wtc1, CLINE_DIM, 0, 960 },
        { Wc2, Wtc2, 256,       0, 256 },
    }};
    convert_wt8_kernel<<<dim3(256, 8), 256, 0, stream>>>(jobs);
    concat3_kernel<<<3, 256, 0, stream>>>(bq1, bk1, bv1, bias1);
    concat3_kernel<<<3, 256, 0, stream>>>(bq2, bk2, bv2, bias2);

    // ===================== CSR build =====================
    hipMemsetAsync(degcur, 0, N_NODES * sizeof(int), stream);
    hist_kernel<<<(N_EDGES + 255) / 256, 256, 0, stream>>>(dstp, degcur, N_EDGES);
    const int NB1 = (N_NODES + 1023) / 1024;
    scan1_kernel<<<NB1, 256, 0, stream>>>(degcur, rowptr, bsum, N_NODES);
    scan2_kernel<<<1, 256, 0, stream>>>(bsum, bsume, NB1);
    scan3_kernel<<<(N_NODES + 255) / 256, 256, 0, stream>>>(rowptr, degcur, bsume, N_NODES, N_EDGES);
    scatter_kernel<<<(N_EDGES + 255) / 256, 256, 0, stream>>>(srcp, dstp, degcur, esrc, N_EDGES);

    // ===================== drug layer 1 =====================
    mfma_gemm_kernel<0, bf16><<<nwgN, 256, 0, stream>>>(
        drug_xb, Wt1, bias1, nullptr, qkv, N_NODES, 128, PS, 3, nwgN);
    // attnout1 (relu'd) -> compact [N,256] into h1 slot, with fused BN1 stats
    hipMemsetAsync(bnsum, 0, 512 * sizeof(float), stream);
    attn_fused_kernel<<<2048, 256, 0, stream>>>(rowptr, esrc, qpl, kpl, vpl, h1,
                                                bnsum, bnsumsq, N_NODES);
    // fold BN1 into Wt2/bias2 (in place), export s1/t1 for the residual path
    bn_fold_kernel<<<768, 256, 0, stream>>>(Wt2, bias2, bias2, bnsum, bnsumsq,
                                            g1, be1, s1buf, t1buf, 1.0f / N_NODES);

    // ===================== drug layer 2 =====================
    mfma_gemm_kernel<0, bf16><<<nwgN, 256, 0, stream>>>(
        h1, Wt2, bias2, nullptr, qkv, N_NODES, 256, PS, 3, nwgN);
    // attnout2 -> in-place q-plane (compact), with fused BN2 stats
    hipMemsetAsync(bnsum, 0, 512 * sizeof(float), stream);
    attn_fused_kernel<<<2048, 256, 0, stream>>>(rowptr, esrc, qpl, kpl, vpl, qpl,
                                                bnsum, bnsumsq, N_NODES);
    // fused: pooled = sc2*mean(attnout2) + s1*mean(attnout1) + sh2 + t1
    pool_bn_kernel<<<N_GRAPH, 256, 0, stream>>>(qpl, h1, ibatch, bnsum, bnsumsq,
                                                g2, be2, s1buf, t1buf, out_pool,
                                                1.0f / N_NODES);

    // ===================== cline branch (qkv region now dead) =====================
    convert_a_kernel<<<(B_CL * 960 + 255) / 256, 256, 0, stream>>>(
        cline_x, cline_xb, CLINE_DIM, 960, B_CL * 960);
    mfma_gemm_kernel<1, bf16><<<nwgB, 256, 0, stream>>>(
        cline_xb, Wtc1, bc1, nullptr, c1b, B_CL, 960, 0, 1, nwgB);  // tanh, bf16
    hipMemsetAsync(bnsum, 0, 512 * sizeof(float), stream);
    col_stats_kernel<bf16><<<(B_CL + 63) / 64, 256, 0, stream>>>(c1b, bnsum, bnsumsq, B_CL);
    bn_fold_kernel<<<256, 256, 0, stream>>>(Wtc2, bc2, bc2f, bnsum, bnsumsq,
                                            gc, bec, nullptr, nullptr, 1.0f / B_CL);
    // out_c = c1 + relu(c1 @ Wc2f^T + bc2f)
    mfma_gemm_kernel<2, float><<<nwgB, 256, 0, stream>>>(
        c1b, Wtc2, bc2f, c1b, out_c, B_CL, 256, 0, 1, nwgB);
}

// Round 16
// 471.861 us; speedup vs baseline: 1.3120x; 1.2721x over previous
//
#include <hip/hip_runtime.h>
#include <hip/hip_bf16.h>

// Problem constants (match reference)
static constexpr int N_NODES  = 100000;
static constexpr int N_EDGES  = 400000;
static constexpr int DRUG_DIM = 75;
static constexpr int OUT_C    = 256;   // OUT
static constexpr int N_GRAPH  = 2048;  // G
static constexpr int B_CL     = 2048;  // B
static constexpr int CLINE_DIM= 954;

using bf16 = __hip_bfloat16;
using short8 = __attribute__((ext_vector_type(8))) short;
using f32x4  = __attribute__((ext_vector_type(4))) float;

template<class A, class B> struct is_same_t { static constexpr bool v = false; };
template<class A> struct is_same_t<A, A>   { static constexpr bool v = true;  };

// ---------- load/store helpers ----------
__device__ __forceinline__ float ldf(const float* p) { return *p; }
__device__ __forceinline__ float ldf(const bf16* p)  { return __bfloat162float(*p); }
__device__ __forceinline__ void  stf(float* p, float v) { *p = v; }
__device__ __forceinline__ void  stf(bf16* p, float v)  { *p = __float2bfloat16(v); }
__device__ __forceinline__ float bfu(unsigned short u) { return __uint_as_float(((unsigned)u) << 16); }
__device__ __forceinline__ unsigned short f2bu(float f) {
    bf16 h = __float2bfloat16(f);
    return *reinterpret_cast<unsigned short*>(&h);
}

// async global -> LDS, 16B per lane; LDS dest = uniform base + lane*16
__device__ __forceinline__ void gload_lds16(const void* g, void* l) {
    __builtin_amdgcn_global_load_lds(
        (const __attribute__((address_space(1))) void*)g,
        (__attribute__((address_space(3))) void*)l, 16, 0, 0);
}

// ================= input/weight prep =================
__global__ __launch_bounds__(256)
void convert_a_kernel(const float* __restrict__ A, bf16* __restrict__ Ab,
                      int K, int Kpad, int total)
{
    int idx = blockIdx.x * 256 + threadIdx.x;
    if (idx >= total) return;
    int r = idx / Kpad, k = idx - r * Kpad;
    float f = (k < K) ? A[(size_t)r * K + k] : 0.f;
    Ab[idx] = __float2bfloat16(f);
}

// all weight transposes in one launch; NW is always 256
struct WtJob  { const float* W; bf16* Wt; int K; int n0; int Kpad; };
struct WtJobs { WtJob j[8]; };
__global__ __launch_bounds__(256)
void convert_wt8_kernel(WtJobs jobs)
{
    WtJob jb = jobs.j[blockIdx.y];
    int n = blockIdx.x;
    for (int k = threadIdx.x; k < jb.Kpad; k += 256) {
        float f = (k < jb.K) ? jb.W[(size_t)k * 256 + n] : 0.f;
        jb.Wt[(size_t)(jb.n0 + n) * jb.Kpad + k] = __float2bfloat16(f);
    }
}

__global__ __launch_bounds__(256)
void concat3_kernel(const float* __restrict__ a, const float* __restrict__ b,
                    const float* __restrict__ c, float* __restrict__ out)
{
    int i = blockIdx.x * 256 + threadIdx.x;
    if (i < 256)      out[i] = a[i];
    else if (i < 512) out[i] = b[i - 256];
    else if (i < 768) out[i] = c[i - 512];
}

// ================= MFMA GEMM (single-buffer global_load_lds, 128x128 tile) ====
// r6/r8-proven core (measured 2.31 TB/s pace) + XCD swizzle + plane-split.
// 1D grid, bijective XCD swizzle (m204): each XCD gets a contiguous wgid range,
// ntile fastest -> the NTILES blocks sharing an A-tile run on the SAME XCD L2.
// Output col slab [ntile*128,+128) -> plane (ntile>>1), col (ntile&1)*128+...,
// plane base C + (ntile>>1)*PS, row stride 256.
// A bf16 [M][K], K mult of 64, M mult of 8. Tile 128x128, BK=64, 4 waves (2x2).
// LDS relation: LDS[row][y] = data[row][y ^ ((row&7)<<3)] via pre-swizzled
// global source element (LDS dest stays linear).
template<int ACT, typename TO>
__global__ __launch_bounds__(256)
void mfma_gemm_kernel(const bf16* __restrict__ A, const bf16* __restrict__ Wt,
                      const float* __restrict__ bias, const bf16* __restrict__ res,
                      TO* __restrict__ C, int M, int K, size_t PS,
                      int NTILES, int nwg)
{
    __shared__ alignas(16) short As[128 * 64];   // 16 KB
    __shared__ alignas(16) short Bs[128 * 64];   // 16 KB

    // bijective XCD swizzle
    const int id  = blockIdx.x;
    const int qq  = nwg >> 3, rr = nwg & 7;
    const int xcd = id & 7, loc = id >> 3;
    const int wgid = (xcd < rr ? xcd * (qq + 1) : rr * (qq + 1) + (xcd - rr) * qq) + loc;
    const int ntile = wgid % NTILES, mtile = wgid / NTILES;

    const int tid = threadIdx.x;
    const int lane = tid & 63, wid = tid >> 6;
    const int wr = wid >> 1, wc = wid & 1;

    f32x4 acc[4][4] = {};

    for (int k0 = 0; k0 < K; k0 += 64) {
        // 4 A-issues + 4 B-issues per wave, 8 rows per issue
        #pragma unroll
        for (int i = 0; i < 4; ++i) {
            const int chunk = i * 4 + wid;            // wave-uniform
            const int row   = chunk * 8 + (lane >> 3);
            const int e     = ((lane & 7) ^ (row & 7)) << 3;
            if (mtile * 128 + chunk * 8 + 8 <= M)     // wave-uniform guard (M%8==0)
                gload_lds16(A + (size_t)(mtile * 128 + row) * K + k0 + e,
                            &As[chunk * 512]);
            gload_lds16(Wt + (size_t)(ntile * 128 + row) * K + k0 + e,
                        &Bs[chunk * 512]);
        }
        __syncthreads();   // drains vmcnt(0): LDS tiles ready
        #pragma unroll
        for (int kk = 0; kk < 2; ++kk) {
            const int coff = (kk * 32 + (lane >> 4) * 8) ^ ((lane & 7) << 3);
            short8 a[4], b[4];
            #pragma unroll
            for (int m = 0; m < 4; ++m)
                a[m] = *reinterpret_cast<const short8*>(
                    &As[(wr * 64 + m * 16 + (lane & 15)) * 64 + coff]);
            #pragma unroll
            for (int n = 0; n < 4; ++n)
                b[n] = *reinterpret_cast<const short8*>(
                    &Bs[(wc * 64 + n * 16 + (lane & 15)) * 64 + coff]);
            #pragma unroll
            for (int m = 0; m < 4; ++m)
                #pragma unroll
                for (int n = 0; n < 4; ++n)
                    acc[m][n] = __builtin_amdgcn_mfma_f32_16x16x32_bf16(
                        a[m], b[n], acc[m][n], 0, 0, 0);
        }
        __syncthreads();
    }

    // epilogue: C/D layout col=lane&15, row=(lane>>4)*4+reg
    TO* Cp = C + (size_t)(ntile >> 1) * PS;     // plane base
    const int colbase = (ntile & 1) * 128;      // col offset within plane
    if constexpr (is_same_t<TO, bf16>::v) {
        // per-wave private 8KB bounce region in the (now dead) As/Bs
        short* eb = (wid < 2 ? As : Bs) + (wid & 1) * 4096;
        #pragma unroll
        for (int m = 0; m < 4; ++m)
            #pragma unroll
            for (int n = 0; n < 4; ++n) {
                int col_l = n * 16 + (lane & 15);
                float bcol = bias[ntile * 128 + wc * 64 + col_l];
                #pragma unroll
                for (int r = 0; r < 4; ++r) {
                    int row_l = m * 16 + ((lane >> 4) << 2) + r;
                    float val = acc[m][n][r] + bcol;
                    if (ACT == 1) val = tanhf(val);
                    if (ACT == 2) val = fmaxf(val, 0.f);
                    eb[row_l * 64 + (col_l ^ ((row_l & 7) << 3))] = (short)f2bu(val);
                }
            }
        // read back coalesced: 8 lanes per row, 16B per lane (wave-private)
        #pragma unroll
        for (int i = 0; i < 8; ++i) {
            int row_l = i * 8 + (lane >> 3);
            int row_g = mtile * 128 + wr * 64 + row_l;
            short8 vr = *reinterpret_cast<const short8*>(
                &eb[row_l * 64 + ((((lane & 7) << 3)) ^ ((row_l & 7) << 3))]);
            if (row_g < M)
                *reinterpret_cast<short8*>(
                    &Cp[(size_t)row_g * 256 + colbase + wc * 64 + ((lane & 7) << 3)]) = vr;
        }
    } else {
        #pragma unroll
        for (int m = 0; m < 4; ++m) {
            int row0 = mtile * 128 + wr * 64 + m * 16 + ((lane >> 4) << 2);
            #pragma unroll
            for (int n = 0; n < 4; ++n) {
                int col_l = wc * 64 + n * 16 + (lane & 15);
                float bcol = bias[ntile * 128 + col_l];
                #pragma unroll
                for (int r = 0; r < 4; ++r) {
                    int row = row0 + r;
                    if (row < M) {
                        float val = acc[m][n][r] + bcol;
                        if (ACT == 1) val = tanhf(val);
                        if (ACT == 2) val = fmaxf(val, 0.f);
                        if (res) val += ldf(&res[(size_t)row * 256 + colbase + col_l]);
                        stf(&Cp[(size_t)row * 256 + colbase + col_l], val);
                    }
                }
            }
        }
    }
}

// ================= CSR build =================
__global__ __launch_bounds__(256)
void hist_kernel(const int* __restrict__ dst, int* __restrict__ deg, int E)
{
    int e = blockIdx.x * 256 + threadIdx.x;
    if (e < E) atomicAdd(&deg[dst[e]], 1);
}

__global__ __launch_bounds__(256)
void scan1_kernel(const int* __restrict__ deg, int* __restrict__ part,
                  int* __restrict__ bsum, int n)
{
    __shared__ int sh[256];
    const int t = threadIdx.x;
    const int b0 = blockIdx.x * 1024;
    int v[4]; int s = 0;
    #pragma unroll
    for (int j = 0; j < 4; ++j) {
        int idx = b0 + t * 4 + j;
        v[j] = (idx < n) ? deg[idx] : 0;
        s += v[j];
    }
    sh[t] = s; __syncthreads();
    for (int off = 1; off < 256; off <<= 1) {
        int x = (t >= off) ? sh[t - off] : 0;
        __syncthreads();
        sh[t] += x;
        __syncthreads();
    }
    if (t == 255) bsum[blockIdx.x] = sh[255];
    int run = sh[t] - s;
    #pragma unroll
    for (int j = 0; j < 4; ++j) {
        int idx = b0 + t * 4 + j;
        if (idx < n) part[idx] = run;
        run += v[j];
    }
}

__global__ __launch_bounds__(256)
void scan2_kernel(const int* __restrict__ bsum, int* __restrict__ bsume, int nb)
{
    __shared__ int sh[256];
    const int t = threadIdx.x;
    int x0 = (t < nb) ? bsum[t] : 0;
    sh[t] = x0; __syncthreads();
    for (int off = 1; off < 256; off <<= 1) {
        int x = (t >= off) ? sh[t - off] : 0;
        __syncthreads();
        sh[t] += x;
        __syncthreads();
    }
    if (t < nb) bsume[t] = sh[t] - x0;
}

__global__ __launch_bounds__(256)
void scan3_kernel(int* __restrict__ rowptr, int* __restrict__ cursor,
                  const int* __restrict__ bsume, int n, int E)
{
    int idx = blockIdx.x * 256 + threadIdx.x;
    if (idx < n) {
        int val = rowptr[idx] + bsume[idx >> 10];
        rowptr[idx] = val;
        cursor[idx] = val;
    }
    if (idx == 0) rowptr[n] = E;
}

__global__ __launch_bounds__(256)
void scatter_kernel(const int* __restrict__ src, const int* __restrict__ dst,
                    int* __restrict__ cursor, int* __restrict__ esrc, int E)
{
    int e = blockIdx.x * 256 + threadIdx.x;
    if (e < E) {
        int slot = atomicAdd(&cursor[dst[e]], 1);
        esrc[slot] = src[e];
    }
}

// ================= fused attention + BN column stats (CSR gather, planes) =====
// Grid-stride (launch 4096 blocks x 4 waves; ~6 nodes/wave). Lane owns the SAME
// 4 channels for every node -> per-lane register sum/sumsq; end-of-kernel LDS
// cross-wave reduce + 512 atomics into stats slice (blockIdx&7) -- 8-slice
// split keeps per-address contention flat. Replaces the col_stats pass.
// 2-edge unroll + branchy rescale (numerically identical to always-rescale).
__global__ __launch_bounds__(256)
void attn_fused_kernel(const int* __restrict__ rowptr, const int* __restrict__ esrc,
                       const bf16* __restrict__ q, const bf16* __restrict__ k,
                       const bf16* __restrict__ v, bf16* __restrict__ out,
                       float* __restrict__ stats, int n)
{
    __shared__ float red[8][256];   // [wid]=sum, [wid+4]=sumsq; 8 KB
    const int lane = threadIdx.x & 63;
    const int wid  = threadIdx.x >> 6;

    float cs0 = 0.f, cs1 = 0.f, cs2 = 0.f, cs3 = 0.f;
    float cq0 = 0.f, cq1 = 0.f, cq2 = 0.f, cq3 = 0.f;

    const int stride = gridDim.x * 4;
    for (int node = blockIdx.x * 4 + wid; node < n; node += stride) {
        int lo = rowptr[node], hi = rowptr[node + 1];

        ushort4 qu = ((const ushort4*)(q + (size_t)node * 256))[lane];
        float q0 = bfu(qu.x), q1 = bfu(qu.y), q2 = bfu(qu.z), q3 = bfu(qu.w);

        float m = -INFINITY, s = 0.f;
        float a0 = 0.f, a1 = 0.f, a2 = 0.f, a3 = 0.f;

        auto upd = [&](float l, ushort4 vu) {
            if (l > m) {
                float sc = __expf(m - l);      // exp(-inf)=0 handles first edge
                a0 *= sc; a1 *= sc; a2 *= sc; a3 *= sc; s *= sc;
                m = l;
            }
            float e = __expf(l - m);
            a0 = fmaf(e, bfu(vu.x), a0);
            a1 = fmaf(e, bfu(vu.y), a1);
            a2 = fmaf(e, bfu(vu.z), a2);
            a3 = fmaf(e, bfu(vu.w), a3);
            s += e;
        };

        int i = lo;
        for (; i + 2 <= hi; i += 2) {
            int sn0 = esrc[i], sn1 = esrc[i + 1];
            ushort4 ku0 = ((const ushort4*)(k + (size_t)sn0 * 256))[lane];
            ushort4 vu0 = ((const ushort4*)(v + (size_t)sn0 * 256))[lane];
            ushort4 ku1 = ((const ushort4*)(k + (size_t)sn1 * 256))[lane];
            ushort4 vu1 = ((const ushort4*)(v + (size_t)sn1 * 256))[lane];
            float p0 = q0 * bfu(ku0.x);
            p0 = fmaf(q1, bfu(ku0.y), p0);
            p0 = fmaf(q2, bfu(ku0.z), p0);
            p0 = fmaf(q3, bfu(ku0.w), p0);
            float p1 = q0 * bfu(ku1.x);
            p1 = fmaf(q1, bfu(ku1.y), p1);
            p1 = fmaf(q2, bfu(ku1.z), p1);
            p1 = fmaf(q3, bfu(ku1.w), p1);
            p0 += __shfl_xor(p0, 1);  p1 += __shfl_xor(p1, 1);
            p0 += __shfl_xor(p0, 2);  p1 += __shfl_xor(p1, 2);
            p0 += __shfl_xor(p0, 4);  p1 += __shfl_xor(p1, 4);
            p0 += __shfl_xor(p0, 8);  p1 += __shfl_xor(p1, 8);
            upd(p0 * 0.125f, vu0);
            upd(p1 * 0.125f, vu1);
        }
        if (i < hi) {
            int sn = esrc[i];
            ushort4 ku = ((const ushort4*)(k + (size_t)sn * 256))[lane];
            ushort4 vu = ((const ushort4*)(v + (size_t)sn * 256))[lane];
            float p = q0 * bfu(ku.x);
            p = fmaf(q1, bfu(ku.y), p);
            p = fmaf(q2, bfu(ku.z), p);
            p = fmaf(q3, bfu(ku.w), p);
            p += __shfl_xor(p, 1);
            p += __shfl_xor(p, 2);
            p += __shfl_xor(p, 4);
            p += __shfl_xor(p, 8);
            upd(p * 0.125f, vu);
        }

        float inv = 1.f / (s + 1e-16f);
        ushort4 o;
        o.x = f2bu(fmaxf(a0 * inv, 0.f));
        o.y = f2bu(fmaxf(a1 * inv, 0.f));
        o.z = f2bu(fmaxf(a2 * inv, 0.f));
        o.w = f2bu(fmaxf(a3 * inv, 0.f));
        ((ushort4*)(out + (size_t)node * 256))[lane] = o;

        // stats from the bf16-rounded values (bit-identical to a read-back)
        float r0 = bfu(o.x), r1 = bfu(o.y), r2 = bfu(o.z), r3 = bfu(o.w);
        cs0 += r0; cq0 += r0 * r0;
        cs1 += r1; cq1 += r1 * r1;
        cs2 += r2; cq2 += r2 * r2;
        cs3 += r3; cq3 += r3 * r3;
    }

    // cross-wave reduce: lane owns channels 4*lane..4*lane+3
    red[wid][lane * 4 + 0] = cs0;  red[wid + 4][lane * 4 + 0] = cq0;
    red[wid][lane * 4 + 1] = cs1;  red[wid + 4][lane * 4 + 1] = cq1;
    red[wid][lane * 4 + 2] = cs2;  red[wid + 4][lane * 4 + 2] = cq2;
    red[wid][lane * 4 + 3] = cs3;  red[wid + 4][lane * 4 + 3] = cq3;
    __syncthreads();
    int t = threadIdx.x;
    float ssum = red[0][t] + red[1][t] + red[2][t] + red[3][t];
    float sqq  = red[4][t] + red[5][t] + red[6][t] + red[7][t];
    float* sl = stats + (size_t)(blockIdx.x & 7) * 512;
    atomicAdd(&sl[t], ssum);
    atomicAdd(&sl[256 + t], sqq);
}

// ---------- per-channel BN stats (compact [M,256]) — cline branch (slice 0) ----
template<typename TX>
__global__ __launch_bounds__(256)
void col_stats_kernel(const TX* __restrict__ x, float* __restrict__ stats, int M)
{
    const int c = threadIdx.x;
    const int r0 = blockIdx.x * 64;
    const int r1 = min(r0 + 64, M);
    float ls = 0.f, lq = 0.f;
    for (int r = r0; r < r1; ++r) {
        float val = ldf(&x[(size_t)r * 256 + c]);
        ls += val;
        lq += val * val;
    }
    atomicAdd(&stats[c], ls);
    atomicAdd(&stats[256 + c], lq);
}

// ---------- BN fold into following weights (sums the 8 stats slices) ----------
__global__ __launch_bounds__(256)
void bn_fold_kernel(bf16* __restrict__ Wt, const float* __restrict__ bin,
                    float* __restrict__ bout, const float* __restrict__ stats,
                    const float* __restrict__ g, const float* __restrict__ be,
                    float* __restrict__ s_out, float* __restrict__ t_out, float invM)
{
    __shared__ float sh[256];
    const int n = blockIdx.x, k = threadIdx.x;
    float sum = 0.f, sq = 0.f;
    #pragma unroll
    for (int s = 0; s < 8; ++s) {
        sum += stats[s * 512 + k];
        sq  += stats[s * 512 + 256 + k];
    }
    float mu  = sum * invM;
    float var = sq * invM - mu * mu;
    float scale = g[k] * rsqrtf(var + 1e-5f);
    float shift = be[k] - mu * scale;
    float w = ldf(&Wt[(size_t)n * 256 + k]);
    Wt[(size_t)n * 256 + k] = __float2bfloat16(w * scale);
    sh[k] = shift * w;
    __syncthreads();
    for (int off = 128; off; off >>= 1) {
        if (k < off) sh[k] += sh[k + off];
        __syncthreads();
    }
    if (k == 0) bout[n] = bin[n] + sh[0];
    if (s_out && n == 0) { s_out[k] = scale; t_out[k] = shift; }
}

// ---------- fused bn2 + residual + segment-mean pool (sums 8 stats slices) ----
__global__ __launch_bounds__(256)
void pool_bn_kernel(const bf16* __restrict__ a2, const bf16* __restrict__ h1,
                    const int* __restrict__ ibatch, const float* __restrict__ stats,
                    const float* __restrict__ g2, const float* __restrict__ be2,
                    const float* __restrict__ s1, const float* __restrict__ t1,
                    float* __restrict__ out, float invM)
{
    int g = blockIdx.x;
    __shared__ int bounds[2];
    if (threadIdx.x == 0) {
        int lo = 0, hi = N_NODES;
        while (lo < hi) { int mid = (lo + hi) >> 1; if (ibatch[mid] < g) lo = mid + 1; else hi = mid; }
        bounds[0] = lo;
        int lo2 = lo, hi2 = N_NODES;
        while (lo2 < hi2) { int mid = (lo2 + hi2) >> 1; if (ibatch[mid] < g + 1) lo2 = mid + 1; else hi2 = mid; }
        bounds[1] = lo2;
    }
    __syncthreads();
    int lo = bounds[0], hi = bounds[1];
    int c = threadIdx.x;
    float sa = 0.f, sh = 0.f;
    for (int r = lo; r < hi; ++r) {
        sa += ldf(&a2[(size_t)r * 256 + c]);
        sh += ldf(&h1[(size_t)r * 256 + c]);
    }
    float sum = 0.f, sq = 0.f;
    #pragma unroll
    for (int s = 0; s < 8; ++s) {
        sum += stats[s * 512 + c];
        sq  += stats[s * 512 + 256 + c];
    }
    float mu  = sum * invM;
    float var = sq * invM - mu * mu;
    float sc2 = g2[c] * rsqrtf(var + 1e-5f);
    float sh2 = be2[c] - mu * sc2;
    int cnt = hi - lo;
    out[(size_t)g * 256 + c] =
        (cnt > 0) ? (sc2 * sa + s1[c] * sh) / cnt + sh2 + t1[c] : 0.f;
}

extern "C" void kernel_launch(void* const* d_in, const int* in_sizes, int n_in,
                              void* d_out, int out_size, void* d_ws, size_t ws_size,
                              hipStream_t stream)
{
    const float* drug_x  = (const float*)d_in[0];
    const int*   adj     = (const int*)  d_in[1];
    const int*   ibatch  = (const int*)  d_in[2];
    const float* cline_x = (const float*)d_in[3];
    const float* Wq1 = (const float*)d_in[4];  const float* bq1 = (const float*)d_in[5];
    const float* Wk1 = (const float*)d_in[6];  const float* bk1 = (const float*)d_in[7];
    const float* Wv1 = (const float*)d_in[8];  const float* bv1 = (const float*)d_in[9];
    const float* g1  = (const float*)d_in[10]; const float* be1 = (const float*)d_in[11];
    const float* Wq2 = (const float*)d_in[12]; const float* bq2 = (const float*)d_in[13];
    const float* Wk2 = (const float*)d_in[14]; const float* bk2 = (const float*)d_in[15];
    const float* Wv2 = (const float*)d_in[16]; const float* bv2 = (const float*)d_in[17];
    const float* g2  = (const float*)d_in[18]; const float* be2 = (const float*)d_in[19];
    const float* Wc1 = (const float*)d_in[20]; const float* bc1 = (const float*)d_in[21];
    const float* gc  = (const float*)d_in[22]; const float* bec = (const float*)d_in[23];
    const float* Wc2 = (const float*)d_in[24]; const float* bc2 = (const float*)d_in[25];

    const int* srcp = adj;
    const int* dstp = adj + N_EDGES;

    // ---- workspace arena (~209 MB) ----
    char* p = (char*)d_ws;
    auto take = [&p](size_t bytes) {
        char* r = p;
        p += (bytes + 15) & ~(size_t)15;
        return r;
    };
    const size_t PS = (size_t)N_NODES * 256;   // plane stride (elements)
    bf16*  qkv   = (bf16*)take(PS * 3 * sizeof(bf16));   // planes q|k|v; attn2 out in q-plane
    bf16*  h1    = (bf16*)take(PS * sizeof(bf16));       // drug_xb -> attnout1
    int*   rowptr= (int*)take((size_t)(N_NODES + 1) * sizeof(int));
    int*   degcur= (int*)take((size_t)N_NODES * sizeof(int));
    int*   bsum  = (int*)take(256 * sizeof(int));
    int*   bsume = (int*)take(256 * sizeof(int));
    int*   esrc  = (int*)take((size_t)N_EDGES * sizeof(int));
    float* stats = (float*)take(8 * 512 * sizeof(float));   // 8-slice sum/sumsq
    float* s1buf = (float*)take(256 * sizeof(float));
    float* t1buf = (float*)take(256 * sizeof(float));
    bf16*  Wt1   = (bf16*)take((size_t)768 * 128 * sizeof(bf16));
    bf16*  Wt2   = (bf16*)take((size_t)768 * 256 * sizeof(bf16));
    bf16*  Wtc1  = (bf16*)take((size_t)256 * 960 * sizeof(bf16));
    bf16*  Wtc2  = (bf16*)take((size_t)256 * 256 * sizeof(bf16));
    float* bc2f  = (float*)take(256 * sizeof(float));
    float* bias1 = (float*)take(768 * sizeof(float));
    float* bias2 = (float*)take(768 * sizeof(float));
    size_t needed = (size_t)(p - (char*)d_ws);
    if (ws_size < needed) return;

    // aliases (lifetime-disjoint):
    bf16* drug_xb  = h1;                       // [N,128] bf16, dead before L1 attn writes
    bf16* cline_xb = qkv;                      // [2048,960] bf16 (qkv dead after pool)
    bf16* c1b      = qkv + (size_t)2048 * 960; // [2048,256] bf16 tanh output

    bf16* qpl = qkv;            // q plane
    bf16* kpl = qkv + PS;       // k plane
    bf16* vpl = qkv + 2 * PS;   // v plane

    float* out_pool = (float*)d_out;                      // [G,256]
    float* out_c    = out_pool + (size_t)N_GRAPH * OUT_C; // [B,256]

    const int MT_N = (N_NODES + 127) / 128;  // 782 mtiles
    const int nwgN = 6 * MT_N;               // drug GEMM: 6 ntiles (768/128)
    const int nwgB = 2 * (B_CL / 128);       // 32 (NTILES=2)

    // ===================== prep =====================
    convert_a_kernel<<<(N_NODES * 128 + 255) / 256, 256, 0, stream>>>(
        drug_x, drug_xb, DRUG_DIM, 128, N_NODES * 128);
    WtJobs jobs = {{
        { Wq1, Wt1, DRUG_DIM,   0, 128 },
        { Wk1, Wt1, DRUG_DIM, 256, 128 },
        { Wv1, Wt1, DRUG_DIM, 512, 128 },
        { Wq2, Wt2, 256,        0, 256 },
        { Wk2, Wt2, 256,      256, 256 },
        { Wv2, Wt2, 256,      512, 256 },
        { Wc1, Wtc1, CLINE_DIM, 0, 960 },
        { Wc2, Wtc2, 256,       0, 256 },
    }};
    convert_wt8_kernel<<<dim3(256, 8), 256, 0, stream>>>(jobs);
    concat3_kernel<<<3, 256, 0, stream>>>(bq1, bk1, bv1, bias1);
    concat3_kernel<<<3, 256, 0, stream>>>(bq2, bk2, bv2, bias2);

    // ===================== CSR build =====================
    hipMemsetAsync(degcur, 0, N_NODES * sizeof(int), stream);
    hist_kernel<<<(N_EDGES + 255) / 256, 256, 0, stream>>>(dstp, degcur, N_EDGES);
    const int NB1 = (N_NODES + 1023) / 1024;
    scan1_kernel<<<NB1, 256, 0, stream>>>(degcur, rowptr, bsum, N_NODES);
    scan2_kernel<<<1, 256, 0, stream>>>(bsum, bsume, NB1);
    scan3_kernel<<<(N_NODES + 255) / 256, 256, 0, stream>>>(rowptr, degcur, bsume, N_NODES, N_EDGES);
    scatter_kernel<<<(N_EDGES + 255) / 256, 256, 0, stream>>>(srcp, dstp, degcur, esrc, N_EDGES);

    // ===================== drug layer 1 =====================
    mfma_gemm_kernel<0, bf16><<<nwgN, 256, 0, stream>>>(
        drug_xb, Wt1, bias1, nullptr, qkv, N_NODES, 128, PS, 6, nwgN);
    // attnout1 (relu'd) -> compact [N,256] into h1 slot, with fused BN1 stats
    hipMemsetAsync(stats, 0, 8 * 512 * sizeof(float), stream);
    attn_fused_kernel<<<4096, 256, 0, stream>>>(rowptr, esrc, qpl, kpl, vpl, h1,
                                                stats, N_NODES);
    // fold BN1 into Wt2/bias2 (in place), export s1/t1 for the residual path
    bn_fold_kernel<<<768, 256, 0, stream>>>(Wt2, bias2, bias2, stats,
                                            g1, be1, s1buf, t1buf, 1.0f / N_NODES);

    // ===================== drug layer 2 =====================
    mfma_gemm_kernel<0, bf16><<<nwgN, 256, 0, stream>>>(
        h1, Wt2, bias2, nullptr, qkv, N_NODES, 256, PS, 6, nwgN);
    // attnout2 -> in-place q-plane (compact), with fused BN2 stats
    hipMemsetAsync(stats, 0, 8 * 512 * sizeof(float), stream);
    attn_fused_kernel<<<4096, 256, 0, stream>>>(rowptr, esrc, qpl, kpl, vpl, qpl,
                                                stats, N_NODES);
    // fused: pooled = sc2*mean(attnout2) + s1*mean(attnout1) + sh2 + t1
    pool_bn_kernel<<<N_GRAPH, 256, 0, stream>>>(qpl, h1, ibatch, stats,
                                                g2, be2, s1buf, t1buf, out_pool,
                                                1.0f / N_NODES);

    // ===================== cline branch (qkv region now dead) =====================
    convert_a_kernel<<<(B_CL * 960 + 255) / 256, 256, 0, stream>>>(
        cline_x, cline_xb, CLINE_DIM, 960, B_CL * 960);
    mfma_gemm_kernel<1, bf16><<<nwgB, 256, 0, stream>>>(
        cline_xb, Wtc1, bc1, nullptr, c1b, B_CL, 960, 0, 2, nwgB);  // tanh, bf16
    hipMemsetAsync(stats, 0, 8 * 512 * sizeof(float), stream);
    col_stats_kernel<bf16><<<(B_CL + 63) / 64, 256, 0, stream>>>(c1b, stats, B_CL);
    bn_fold_kernel<<<256, 256, 0, stream>>>(Wtc2, bc2, bc2f, stats,
                                            gc, bec, nullptr, nullptr, 1.0f / B_CL);
    // out_c = c1 + relu(c1 @ Wc2f^T + bc2f)
    mfma_gemm_kernel<2, float><<<nwgB, 256, 0, stream>>>(
        c1b, Wtc2, bc2f, c1b, out_c, B_CL, 256, 0, 2, nwgB);
}

// Round 17
// 457.086 us; speedup vs baseline: 1.3544x; 1.0323x over previous
//
#include <hip/hip_runtime.h>
#include <hip/hip_bf16.h>

// Problem constants (match reference)
static constexpr int N_NODES  = 100000;
static constexpr int N_EDGES  = 400000;
static constexpr int DRUG_DIM = 75;
static constexpr int OUT_C    = 256;   // OUT
static constexpr int N_GRAPH  = 2048;  // G
static constexpr int B_CL     = 2048;  // B
static constexpr int CLINE_DIM= 954;

using bf16 = __hip_bfloat16;
using short8 = __attribute__((ext_vector_type(8))) short;
using f32x4  = __attribute__((ext_vector_type(4))) float;

// ---------- load/store helpers ----------
__device__ __forceinline__ float ldf(const float* p) { return *p; }
__device__ __forceinline__ float ldf(const bf16* p)  { return __bfloat162float(*p); }
__device__ __forceinline__ void  stf(float* p, float v) { *p = v; }
__device__ __forceinline__ void  stf(bf16* p, float v)  { *p = __float2bfloat16(v); }
__device__ __forceinline__ float bfu(unsigned short u) { return __uint_as_float(((unsigned)u) << 16); }
__device__ __forceinline__ unsigned short f2bu(float f) {
    bf16 h = __float2bfloat16(f);
    return *reinterpret_cast<unsigned short*>(&h);
}

// async global -> LDS, 16B per lane; LDS dest = uniform base + lane*16
__device__ __forceinline__ void gload_lds16(const void* g, void* l) {
    __builtin_amdgcn_global_load_lds(
        (const __attribute__((address_space(1))) void*)g,
        (__attribute__((address_space(3))) void*)l, 16, 0, 0);
}

// ================= input prep: two convert jobs in one launch =================
__global__ __launch_bounds__(256)
void convert_a2_kernel(const float* __restrict__ A0, bf16* __restrict__ O0,
                       int K0, int Kp0, int t0, int nb0,
                       const float* __restrict__ A1, bf16* __restrict__ O1,
                       int K1, int Kp1, int t1)
{
    if ((int)blockIdx.x < nb0) {
        int idx = blockIdx.x * 256 + threadIdx.x;
        if (idx >= t0) return;
        int r = idx / Kp0, k = idx - r * Kp0;
        O0[idx] = __float2bfloat16((k < K0) ? A0[(size_t)r * K0 + k] : 0.f);
    } else {
        int idx = (blockIdx.x - nb0) * 256 + threadIdx.x;
        if (idx >= t1) return;
        int r = idx / Kp1, k = idx - r * Kp1;
        O1[idx] = __float2bfloat16((k < K1) ? A1[(size_t)r * K1 + k] : 0.f);
    }
}

// all weight transposes in one launch; NW is always 256
struct WtJob  { const float* W; bf16* Wt; int K; int n0; int Kpad; };
struct WtJobs { WtJob j[8]; };
__global__ __launch_bounds__(256)
void convert_wt8_kernel(WtJobs jobs)
{
    WtJob jb = jobs.j[blockIdx.y];
    int n = blockIdx.x;
    for (int k = threadIdx.x; k < jb.Kpad; k += 256) {
        float f = (k < jb.K) ? jb.W[(size_t)k * 256 + n] : 0.f;
        jb.Wt[(size_t)(jb.n0 + n) * jb.Kpad + k] = __float2bfloat16(f);
    }
}

__global__ __launch_bounds__(256)
void concat3_kernel(const float* __restrict__ a, const float* __restrict__ b,
                    const float* __restrict__ c, float* __restrict__ out)
{
    int i = blockIdx.x * 256 + threadIdx.x;
    if (i < 256)      out[i] = a[i];
    else if (i < 512) out[i] = b[i - 256];
    else if (i < 768) out[i] = c[i - 512];
}

// ================= MFMA GEMM (two independent jobs per launch) ================
// r16-proven core: 128x128 tile, BK=64, 4 waves (2x2), 32KB LDS, single-buffer
// global_load_lds, XCD-aware bijective block swizzle over the WHOLE grid.
// Job select on swizzled wgid: wgid < jA.nwg -> job A, else job B.
// Plane-split output: slab [ntile*128,+128) -> plane (ntile>>1),
// col (ntile&1)*128+..., base C + (ntile>>1)*PS, row stride 256.
// Runtime act: 0 none, 1 tanh, 2 relu. out_f32: fp32 scalar epilogue (+res).
struct GemmJob {
    const bf16* A; const bf16* Wt; const float* bias; const bf16* res;
    char* C; size_t PS; int M, K, NTILES, nwg, act, out_f32;
};
__global__ __launch_bounds__(256)
void mfma_gemm2_kernel(GemmJob jA, GemmJob jB, int nwgTot)
{
    __shared__ alignas(16) short As[128 * 64];   // 16 KB
    __shared__ alignas(16) short Bs[128 * 64];   // 16 KB

    // bijective XCD swizzle over the whole grid
    const int id  = blockIdx.x;
    const int qq  = nwgTot >> 3, rr = nwgTot & 7;
    const int xcd = id & 7, loc = id >> 3;
    int wgid = (xcd < rr ? xcd * (qq + 1) : rr * (qq + 1) + (xcd - rr) * qq) + loc;

    GemmJob J = (wgid < jA.nwg) ? jA : jB;
    if (wgid >= jA.nwg) wgid -= jA.nwg;
    const int ntile = wgid % J.NTILES, mtile = wgid / J.NTILES;
    const int M = J.M, K = J.K;

    const int tid = threadIdx.x;
    const int lane = tid & 63, wid = tid >> 6;
    const int wr = wid >> 1, wc = wid & 1;

    f32x4 acc[4][4] = {};

    for (int k0 = 0; k0 < K; k0 += 64) {
        #pragma unroll
        for (int i = 0; i < 4; ++i) {
            const int chunk = i * 4 + wid;            // wave-uniform
            const int row   = chunk * 8 + (lane >> 3);
            const int e     = ((lane & 7) ^ (row & 7)) << 3;
            if (mtile * 128 + chunk * 8 + 8 <= M)     // wave-uniform guard (M%8==0)
                gload_lds16(J.A + (size_t)(mtile * 128 + row) * K + k0 + e,
                            &As[chunk * 512]);
            gload_lds16(J.Wt + (size_t)(ntile * 128 + row) * K + k0 + e,
                        &Bs[chunk * 512]);
        }
        __syncthreads();   // drains vmcnt(0): LDS tiles ready
        #pragma unroll
        for (int kk = 0; kk < 2; ++kk) {
            const int coff = (kk * 32 + (lane >> 4) * 8) ^ ((lane & 7) << 3);
            short8 a[4], b[4];
            #pragma unroll
            for (int m = 0; m < 4; ++m)
                a[m] = *reinterpret_cast<const short8*>(
                    &As[(wr * 64 + m * 16 + (lane & 15)) * 64 + coff]);
            #pragma unroll
            for (int n = 0; n < 4; ++n)
                b[n] = *reinterpret_cast<const short8*>(
                    &Bs[(wc * 64 + n * 16 + (lane & 15)) * 64 + coff]);
            #pragma unroll
            for (int m = 0; m < 4; ++m)
                #pragma unroll
                for (int n = 0; n < 4; ++n)
                    acc[m][n] = __builtin_amdgcn_mfma_f32_16x16x32_bf16(
                        a[m], b[n], acc[m][n], 0, 0, 0);
        }
        __syncthreads();
    }

    // epilogue: C/D layout col=lane&15, row=(lane>>4)*4+reg
    const int colbase = (ntile & 1) * 128;
    if (!J.out_f32) {
        bf16* Cp = (bf16*)J.C + (size_t)(ntile >> 1) * J.PS;
        short* eb = (wid < 2 ? As : Bs) + (wid & 1) * 4096;   // wave-private 8KB
        #pragma unroll
        for (int m = 0; m < 4; ++m)
            #pragma unroll
            for (int n = 0; n < 4; ++n) {
                int col_l = n * 16 + (lane & 15);
                float bcol = J.bias[ntile * 128 + wc * 64 + col_l];
                #pragma unroll
                for (int r = 0; r < 4; ++r) {
                    int row_l = m * 16 + ((lane >> 4) << 2) + r;
                    float val = acc[m][n][r] + bcol;
                    if (J.act == 1) val = tanhf(val);
                    if (J.act == 2) val = fmaxf(val, 0.f);
                    eb[row_l * 64 + (col_l ^ ((row_l & 7) << 3))] = (short)f2bu(val);
                }
            }
        #pragma unroll
        for (int i = 0; i < 8; ++i) {
            int row_l = i * 8 + (lane >> 3);
            int row_g = mtile * 128 + wr * 64 + row_l;
            short8 vr = *reinterpret_cast<const short8*>(
                &eb[row_l * 64 + ((((lane & 7) << 3)) ^ ((row_l & 7) << 3))]);
            if (row_g < M)
                *reinterpret_cast<short8*>(
                    &Cp[(size_t)row_g * 256 + colbase + wc * 64 + ((lane & 7) << 3)]) = vr;
        }
    } else {
        float* Cp = (float*)J.C + (size_t)(ntile >> 1) * J.PS;
        #pragma unroll
        for (int m = 0; m < 4; ++m) {
            int row0 = mtile * 128 + wr * 64 + m * 16 + ((lane >> 4) << 2);
            #pragma unroll
            for (int n = 0; n < 4; ++n) {
                int col_l = wc * 64 + n * 16 + (lane & 15);
                float bcol = J.bias[ntile * 128 + col_l];
                #pragma unroll
                for (int r = 0; r < 4; ++r) {
                    int row = row0 + r;
                    if (row < M) {
                        float val = acc[m][n][r] + bcol;
                        if (J.act == 1) val = tanhf(val);
                        if (J.act == 2) val = fmaxf(val, 0.f);
                        if (J.res) val += ldf(&J.res[(size_t)row * 256 + colbase + col_l]);
                        stf(&Cp[(size_t)row * 256 + colbase + col_l], val);
                    }
                }
            }
        }
    }
}

// ================= CSR build =================
__global__ __launch_bounds__(256)
void hist_kernel(const int* __restrict__ dst, int* __restrict__ deg, int E)
{
    int e = blockIdx.x * 256 + threadIdx.x;
    if (e < E) atomicAdd(&deg[dst[e]], 1);
}

__global__ __launch_bounds__(256)
void scan1_kernel(const int* __restrict__ deg, int* __restrict__ part,
                  int* __restrict__ bsum, int n)
{
    __shared__ int sh[256];
    const int t = threadIdx.x;
    const int b0 = blockIdx.x * 1024;
    int v[4]; int s = 0;
    #pragma unroll
    for (int j = 0; j < 4; ++j) {
        int idx = b0 + t * 4 + j;
        v[j] = (idx < n) ? deg[idx] : 0;
        s += v[j];
    }
    sh[t] = s; __syncthreads();
    for (int off = 1; off < 256; off <<= 1) {
        int x = (t >= off) ? sh[t - off] : 0;
        __syncthreads();
        sh[t] += x;
        __syncthreads();
    }
    if (t == 255) bsum[blockIdx.x] = sh[255];
    int run = sh[t] - s;
    #pragma unroll
    for (int j = 0; j < 4; ++j) {
        int idx = b0 + t * 4 + j;
        if (idx < n) part[idx] = run;
        run += v[j];
    }
}

__global__ __launch_bounds__(256)
void scan2_kernel(const int* __restrict__ bsum, int* __restrict__ bsume, int nb)
{
    __shared__ int sh[256];
    const int t = threadIdx.x;
    int x0 = (t < nb) ? bsum[t] : 0;
    sh[t] = x0; __syncthreads();
    for (int off = 1; off < 256; off <<= 1) {
        int x = (t >= off) ? sh[t - off] : 0;
        __syncthreads();
        sh[t] += x;
        __syncthreads();
    }
    if (t < nb) bsume[t] = sh[t] - x0;
}

__global__ __launch_bounds__(256)
void scan3_kernel(int* __restrict__ rowptr, int* __restrict__ cursor,
                  const int* __restrict__ bsume, int n, int E)
{
    int idx = blockIdx.x * 256 + threadIdx.x;
    if (idx < n) {
        int val = rowptr[idx] + bsume[idx >> 10];
        rowptr[idx] = val;
        cursor[idx] = val;
    }
    if (idx == 0) rowptr[n] = E;
}

__global__ __launch_bounds__(256)
void scatter_kernel(const int* __restrict__ src, const int* __restrict__ dst,
                    int* __restrict__ cursor, int* __restrict__ esrc, int E)
{
    int e = blockIdx.x * 256 + threadIdx.x;
    if (e < E) {
        int slot = atomicAdd(&cursor[dst[e]], 1);
        esrc[slot] = src[e];
    }
}

// ================= fused attention + BN column stats (CSR gather, planes) =====
// Grid-stride (4096 blocks x 4 waves). Lane owns the SAME 4 channels for every
// node -> per-lane register sum/sumsq; LDS cross-wave reduce + atomics into
// stats slice (blockIdx&7). 2-edge unroll + branchy rescale (numerically
// identical to always-rescale).
__global__ __launch_bounds__(256)
void attn_fused_kernel(const int* __restrict__ rowptr, const int* __restrict__ esrc,
                       const bf16* __restrict__ q, const bf16* __restrict__ k,
                       const bf16* __restrict__ v, bf16* __restrict__ out,
                       float* __restrict__ stats, int n)
{
    __shared__ float red[8][256];   // [wid]=sum, [wid+4]=sumsq; 8 KB
    const int lane = threadIdx.x & 63;
    const int wid  = threadIdx.x >> 6;

    float cs0 = 0.f, cs1 = 0.f, cs2 = 0.f, cs3 = 0.f;
    float cq0 = 0.f, cq1 = 0.f, cq2 = 0.f, cq3 = 0.f;

    const int stride = gridDim.x * 4;
    for (int node = blockIdx.x * 4 + wid; node < n; node += stride) {
        int lo = rowptr[node], hi = rowptr[node + 1];

        ushort4 qu = ((const ushort4*)(q + (size_t)node * 256))[lane];
        float q0 = bfu(qu.x), q1 = bfu(qu.y), q2 = bfu(qu.z), q3 = bfu(qu.w);

        float m = -INFINITY, s = 0.f;
        float a0 = 0.f, a1 = 0.f, a2 = 0.f, a3 = 0.f;

        auto upd = [&](float l, ushort4 vu) {
            if (l > m) {
                float sc = __expf(m - l);      // exp(-inf)=0 handles first edge
                a0 *= sc; a1 *= sc; a2 *= sc; a3 *= sc; s *= sc;
                m = l;
            }
            float e = __expf(l - m);
            a0 = fmaf(e, bfu(vu.x), a0);
            a1 = fmaf(e, bfu(vu.y), a1);
            a2 = fmaf(e, bfu(vu.z), a2);
            a3 = fmaf(e, bfu(vu.w), a3);
            s += e;
        };

        int i = lo;
        for (; i + 2 <= hi; i += 2) {
            int sn0 = esrc[i], sn1 = esrc[i + 1];
            ushort4 ku0 = ((const ushort4*)(k + (size_t)sn0 * 256))[lane];
            ushort4 vu0 = ((const ushort4*)(v + (size_t)sn0 * 256))[lane];
            ushort4 ku1 = ((const ushort4*)(k + (size_t)sn1 * 256))[lane];
            ushort4 vu1 = ((const ushort4*)(v + (size_t)sn1 * 256))[lane];
            float p0 = q0 * bfu(ku0.x);
            p0 = fmaf(q1, bfu(ku0.y), p0);
            p0 = fmaf(q2, bfu(ku0.z), p0);
            p0 = fmaf(q3, bfu(ku0.w), p0);
            float p1 = q0 * bfu(ku1.x);
            p1 = fmaf(q1, bfu(ku1.y), p1);
            p1 = fmaf(q2, bfu(ku1.z), p1);
            p1 = fmaf(q3, bfu(ku1.w), p1);
            p0 += __shfl_xor(p0, 1);  p1 += __shfl_xor(p1, 1);
            p0 += __shfl_xor(p0, 2);  p1 += __shfl_xor(p1, 2);
            p0 += __shfl_xor(p0, 4);  p1 += __shfl_xor(p1, 4);
            p0 += __shfl_xor(p0, 8);  p1 += __shfl_xor(p1, 8);
            upd(p0 * 0.125f, vu0);
            upd(p1 * 0.125f, vu1);
        }
        if (i < hi) {
            int sn = esrc[i];
            ushort4 ku = ((const ushort4*)(k + (size_t)sn * 256))[lane];
            ushort4 vu = ((const ushort4*)(v + (size_t)sn * 256))[lane];
            float p = q0 * bfu(ku.x);
            p = fmaf(q1, bfu(ku.y), p);
            p = fmaf(q2, bfu(ku.z), p);
            p = fmaf(q3, bfu(ku.w), p);
            p += __shfl_xor(p, 1);
            p += __shfl_xor(p, 2);
            p += __shfl_xor(p, 4);
            p += __shfl_xor(p, 8);
            upd(p * 0.125f, vu);
        }

        float inv = 1.f / (s + 1e-16f);
        ushort4 o;
        o.x = f2bu(fmaxf(a0 * inv, 0.f));
        o.y = f2bu(fmaxf(a1 * inv, 0.f));
        o.z = f2bu(fmaxf(a2 * inv, 0.f));
        o.w = f2bu(fmaxf(a3 * inv, 0.f));
        ((ushort4*)(out + (size_t)node * 256))[lane] = o;

        float r0 = bfu(o.x), r1 = bfu(o.y), r2 = bfu(o.z), r3 = bfu(o.w);
        cs0 += r0; cq0 += r0 * r0;
        cs1 += r1; cq1 += r1 * r1;
        cs2 += r2; cq2 += r2 * r2;
        cs3 += r3; cq3 += r3 * r3;
    }

    red[wid][lane * 4 + 0] = cs0;  red[wid + 4][lane * 4 + 0] = cq0;
    red[wid][lane * 4 + 1] = cs1;  red[wid + 4][lane * 4 + 1] = cq1;
    red[wid][lane * 4 + 2] = cs2;  red[wid + 4][lane * 4 + 2] = cq2;
    red[wid][lane * 4 + 3] = cs3;  red[wid + 4][lane * 4 + 3] = cq3;
    __syncthreads();
    int t = threadIdx.x;
    float ssum = red[0][t] + red[1][t] + red[2][t] + red[3][t];
    float sqq  = red[4][t] + red[5][t] + red[6][t] + red[7][t];
    float* sl = stats + (size_t)(blockIdx.x & 7) * 512;
    atomicAdd(&sl[t], ssum);
    atomicAdd(&sl[256 + t], sqq);
}

// ---------- per-channel BN stats (compact [M,256]) — cline branch (slice 0) ----
__global__ __launch_bounds__(256)
void col_stats_kernel(const bf16* __restrict__ x, float* __restrict__ stats, int M)
{
    const int c = threadIdx.x;
    const int r0 = blockIdx.x * 64;
    const int r1 = min(r0 + 64, M);
    float ls = 0.f, lq = 0.f;
    for (int r = r0; r < r1; ++r) {
        float val = ldf(&x[(size_t)r * 256 + c]);
        ls += val;
        lq += val * val;
    }
    atomicAdd(&stats[c], ls);
    atomicAdd(&stats[256 + c], lq);
}

// ---------- merged BN fold (two jobs): Wt[n][k] *= scale[k], bias update ------
struct FoldJob {
    bf16* Wt; const float* bin; float* bout; const float* stats;
    const float* g; const float* be; float* s_out; float* t_out; float invM;
};
__global__ __launch_bounds__(256)
void bn_fold2_kernel(FoldJob a, FoldJob b, int nA)
{
    __shared__ float sh[256];
    const bool isA = ((int)blockIdx.x < nA);
    FoldJob J = isA ? a : b;
    const int n = isA ? blockIdx.x : blockIdx.x - nA;
    const int k = threadIdx.x;
    float sum = 0.f, sq = 0.f;
    #pragma unroll
    for (int s = 0; s < 8; ++s) {
        sum += J.stats[s * 512 + k];
        sq  += J.stats[s * 512 + 256 + k];
    }
    float mu  = sum * J.invM;
    float var = sq * J.invM - mu * mu;
    float scale = J.g[k] * rsqrtf(var + 1e-5f);
    float shift = J.be[k] - mu * scale;
    float w = ldf(&J.Wt[(size_t)n * 256 + k]);
    J.Wt[(size_t)n * 256 + k] = __float2bfloat16(w * scale);
    sh[k] = shift * w;
    __syncthreads();
    for (int off = 128; off; off >>= 1) {
        if (k < off) sh[k] += sh[k + off];
        __syncthreads();
    }
    if (k == 0) J.bout[n] = J.bin[n] + sh[0];
    if (J.s_out && n == 0) { J.s_out[k] = scale; J.t_out[k] = shift; }
}

// ---------- fused bn2 + residual + segment-mean pool (sums 8 stats slices) ----
__global__ __launch_bounds__(256)
void pool_bn_kernel(const bf16* __restrict__ a2, const bf16* __restrict__ h1,
                    const int* __restrict__ ibatch, const float* __restrict__ stats,
                    const float* __restrict__ g2, const float* __restrict__ be2,
                    const float* __restrict__ s1, const float* __restrict__ t1,
                    float* __restrict__ out, float invM)
{
    int g = blockIdx.x;
    __shared__ int bounds[2];
    if (threadIdx.x == 0) {
        int lo = 0, hi = N_NODES;
        while (lo < hi) { int mid = (lo + hi) >> 1; if (ibatch[mid] < g) lo = mid + 1; else hi = mid; }
        bounds[0] = lo;
        int lo2 = lo, hi2 = N_NODES;
        while (lo2 < hi2) { int mid = (lo2 + hi2) >> 1; if (ibatch[mid] < g + 1) lo2 = mid + 1; else hi2 = mid; }
        bounds[1] = lo2;
    }
    __syncthreads();
    int lo = bounds[0], hi = bounds[1];
    int c = threadIdx.x;
    float sa = 0.f, sh = 0.f;
    for (int r = lo; r < hi; ++r) {
        sa += ldf(&a2[(size_t)r * 256 + c]);
        sh += ldf(&h1[(size_t)r * 256 + c]);
    }
    float sum = 0.f, sq = 0.f;
    #pragma unroll
    for (int s = 0; s < 8; ++s) {
        sum += stats[s * 512 + c];
        sq  += stats[s * 512 + 256 + c];
    }
    float mu  = sum * invM;
    float var = sq * invM - mu * mu;
    float sc2 = g2[c] * rsqrtf(var + 1e-5f);
    float sh2 = be2[c] - mu * sc2;
    int cnt = hi - lo;
    out[(size_t)g * 256 + c] =
        (cnt > 0) ? (sc2 * sa + s1[c] * sh) / cnt + sh2 + t1[c] : 0.f;
}

extern "C" void kernel_launch(void* const* d_in, const int* in_sizes, int n_in,
                              void* d_out, int out_size, void* d_ws, size_t ws_size,
                              hipStream_t stream)
{
    const float* drug_x  = (const float*)d_in[0];
    const int*   adj     = (const int*)  d_in[1];
    const int*   ibatch  = (const int*)  d_in[2];
    const float* cline_x = (const float*)d_in[3];
    const float* Wq1 = (const float*)d_in[4];  const float* bq1 = (const float*)d_in[5];
    const float* Wk1 = (const float*)d_in[6];  const float* bk1 = (const float*)d_in[7];
    const float* Wv1 = (const float*)d_in[8];  const float* bv1 = (const float*)d_in[9];
    const float* g1  = (const float*)d_in[10]; const float* be1 = (const float*)d_in[11];
    const float* Wq2 = (const float*)d_in[12]; const float* bq2 = (const float*)d_in[13];
    const float* Wk2 = (const float*)d_in[14]; const float* bk2 = (const float*)d_in[15];
    const float* Wv2 = (const float*)d_in[16]; const float* bv2 = (const float*)d_in[17];
    const float* g2  = (const float*)d_in[18]; const float* be2 = (const float*)d_in[19];
    const float* Wc1 = (const float*)d_in[20]; const float* bc1 = (const float*)d_in[21];
    const float* gc  = (const float*)d_in[22]; const float* bec = (const float*)d_in[23];
    const float* Wc2 = (const float*)d_in[24]; const float* bc2 = (const float*)d_in[25];

    const int* srcp = adj;
    const int* dstp = adj + N_EDGES;

    // ---- workspace arena (~214 MB) ----
    char* p = (char*)d_ws;
    auto take = [&p](size_t bytes) {
        char* r = p;
        p += (bytes + 15) & ~(size_t)15;
        return r;
    };
    const size_t PS = (size_t)N_NODES * 256;   // plane stride (elements)
    bf16*  qkv   = (bf16*)take(PS * 3 * sizeof(bf16));   // planes q|k|v; attn2 out in q-plane
    bf16*  h1    = (bf16*)take(PS * sizeof(bf16));       // drug_xb -> attnout1
    bf16*  cline_xb = (bf16*)take((size_t)B_CL * 960 * sizeof(bf16)); // dedicated (runs || drug)
    bf16*  c1b   = (bf16*)take((size_t)B_CL * 256 * sizeof(bf16));    // dedicated
    int*   rowptr= (int*)take((size_t)(N_NODES + 1) * sizeof(int));
    int*   degcur= (int*)take((size_t)N_NODES * sizeof(int));
    int*   bsum  = (int*)take(256 * sizeof(int));
    int*   bsume = (int*)take(256 * sizeof(int));
    int*   esrc  = (int*)take((size_t)N_EDGES * sizeof(int));
    float* stats = (float*)take(8 * 512 * sizeof(float));   // drug BN stats (8 slices)
    float* statsC= (float*)take(8 * 512 * sizeof(float));   // cline BN stats
    float* s1buf = (float*)take(256 * sizeof(float));
    float* t1buf = (float*)take(256 * sizeof(float));
    bf16*  Wt1   = (bf16*)take((size_t)768 * 128 * sizeof(bf16));
    bf16*  Wt2   = (bf16*)take((size_t)768 * 256 * sizeof(bf16));
    bf16*  Wtc1  = (bf16*)take((size_t)256 * 960 * sizeof(bf16));
    bf16*  Wtc2  = (bf16*)take((size_t)256 * 256 * sizeof(bf16));
    float* bc2f  = (float*)take(256 * sizeof(float));
    float* bias1 = (float*)take(768 * sizeof(float));
    float* bias2 = (float*)take(768 * sizeof(float));
    size_t needed = (size_t)(p - (char*)d_ws);
    if (ws_size < needed) return;

    bf16* drug_xb = h1;         // [N,128] bf16, dead before L1 attn writes
    bf16* qpl = qkv;            // q plane
    bf16* kpl = qkv + PS;       // k plane
    bf16* vpl = qkv + 2 * PS;   // v plane

    float* out_pool = (float*)d_out;                      // [G,256]
    float* out_c    = out_pool + (size_t)N_GRAPH * OUT_C; // [B,256]

    const int MT_N = (N_NODES + 127) / 128;  // 782 mtiles
    const int nwgN = 6 * MT_N;               // drug GEMM: 6 ntiles (768/128)
    const int nwgB = 2 * (B_CL / 128);       // 32 (NTILES=2)

    // ===================== prep =====================
    const int nb_drug = (N_NODES * 128 + 255) / 256;
    const int nb_cl   = (B_CL * 960 + 255) / 256;
    convert_a2_kernel<<<nb_drug + nb_cl, 256, 0, stream>>>(
        drug_x, drug_xb, DRUG_DIM, 128, N_NODES * 128, nb_drug,
        cline_x, cline_xb, CLINE_DIM, 960, B_CL * 960);
    WtJobs jobs = {{
        { Wq1, Wt1, DRUG_DIM,   0, 128 },
        { Wk1, Wt1, DRUG_DIM, 256, 128 },
        { Wv1, Wt1, DRUG_DIM, 512, 128 },
        { Wq2, Wt2, 256,        0, 256 },
        { Wk2, Wt2, 256,      256, 256 },
        { Wv2, Wt2, 256,      512, 256 },
        { Wc1, Wtc1, CLINE_DIM, 0, 960 },
        { Wc2, Wtc2, 256,       0, 256 },
    }};
    convert_wt8_kernel<<<dim3(256, 8), 256, 0, stream>>>(jobs);
    concat3_kernel<<<3, 256, 0, stream>>>(bq1, bk1, bv1, bias1);
    concat3_kernel<<<3, 256, 0, stream>>>(bq2, bk2, bv2, bias2);

    // ===================== CSR build =====================
    hipMemsetAsync(degcur, 0, N_NODES * sizeof(int), stream);
    hist_kernel<<<(N_EDGES + 255) / 256, 256, 0, stream>>>(dstp, degcur, N_EDGES);
    const int NB1 = (N_NODES + 1023) / 1024;
    scan1_kernel<<<NB1, 256, 0, stream>>>(degcur, rowptr, bsum, N_NODES);
    scan2_kernel<<<1, 256, 0, stream>>>(bsum, bsume, NB1);
    scan3_kernel<<<(N_NODES + 255) / 256, 256, 0, stream>>>(rowptr, degcur, bsume, N_NODES, N_EDGES);
    scatter_kernel<<<(N_EDGES + 255) / 256, 256, 0, stream>>>(srcp, dstp, degcur, esrc, N_EDGES);
    hipMemsetAsync(stats, 0, 2 * 8 * 512 * sizeof(float), stream);  // stats + statsC

    // ============ layer 1: drug qkv GEMM || cline GEMM1 (tanh) ============
    GemmJob jDrug1 = { drug_xb, Wt1, bias1, nullptr, (char*)qkv, PS,
                       N_NODES, 128, 6, nwgN, 0, 0 };
    GemmJob jCl1   = { cline_xb, Wtc1, bc1, nullptr, (char*)c1b, 0,
                       B_CL, 960, 2, nwgB, 1, 0 };
    mfma_gemm2_kernel<<<nwgN + nwgB, 256, 0, stream>>>(jDrug1, jCl1, nwgN + nwgB);
    // attnout1 (relu'd) -> compact [N,256] into h1 slot, with fused BN1 stats
    attn_fused_kernel<<<4096, 256, 0, stream>>>(rowptr, esrc, qpl, kpl, vpl, h1,
                                                stats, N_NODES);
    // cline BN stats (independent, tiny)
    col_stats_kernel<<<(B_CL + 63) / 64, 256, 0, stream>>>(c1b, statsC, B_CL);
    // merged fold: BN1 -> Wt2/bias2 (+s1/t1) ; clineBN -> Wtc2/bc2f
    FoldJob fDrug = { Wt2, bias2, bias2, stats, g1, be1, s1buf, t1buf, 1.0f / N_NODES };
    FoldJob fCl   = { Wtc2, bc2, bc2f, statsC, gc, bec, nullptr, nullptr, 1.0f / B_CL };
    bn_fold2_kernel<<<768 + 256, 256, 0, stream>>>(fDrug, fCl, 768);

    // ============ layer 2: drug qkv GEMM || cline GEMM2 (relu+res, fp32) ============
    GemmJob jDrug2 = { h1, Wt2, bias2, nullptr, (char*)qkv, PS,
                       N_NODES, 256, 6, nwgN, 0, 0 };
    GemmJob jCl2   = { c1b, Wtc2, bc2f, c1b, (char*)out_c, 0,
                       B_CL, 256, 2, nwgB, 2, 1 };
    mfma_gemm2_kernel<<<nwgN + nwgB, 256, 0, stream>>>(jDrug2, jCl2, nwgN + nwgB);
    // attnout2 -> in-place q-plane (compact), with fused BN2 stats
    hipMemsetAsync(stats, 0, 8 * 512 * sizeof(float), stream);
    attn_fused_kernel<<<4096, 256, 0, stream>>>(rowptr, esrc, qpl, kpl, vpl, qpl,
                                                stats, N_NODES);
    // fused: pooled = sc2*mean(attnout2) + s1*mean(attnout1) + sh2 + t1
    pool_bn_kernel<<<N_GRAPH, 256, 0, stream>>>(qpl, h1, ibatch, stats,
                                                g2, be2, s1buf, t1buf, out_pool,
                                                1.0f / N_NODES);
}

// Round 18
// 442.767 us; speedup vs baseline: 1.3982x; 1.0323x over previous
//
#include <hip/hip_runtime.h>
#include <hip/hip_bf16.h>

// Problem constants (match reference)
static constexpr int N_NODES  = 100000;
static constexpr int N_EDGES  = 400000;
static constexpr int DRUG_DIM = 75;
static constexpr int OUT_C    = 256;   // OUT
static constexpr int N_GRAPH  = 2048;  // G
static constexpr int B_CL     = 2048;  // B
static constexpr int CLINE_DIM= 954;

using bf16 = __hip_bfloat16;
using short8 = __attribute__((ext_vector_type(8))) short;
using f32x4  = __attribute__((ext_vector_type(4))) float;

// ---------- load/store helpers ----------
__device__ __forceinline__ float ldf(const float* p) { return *p; }
__device__ __forceinline__ float ldf(const bf16* p)  { return __bfloat162float(*p); }
__device__ __forceinline__ void  stf(float* p, float v) { *p = v; }
__device__ __forceinline__ void  stf(bf16* p, float v)  { *p = __float2bfloat16(v); }
__device__ __forceinline__ float bfu(unsigned short u) { return __uint_as_float(((unsigned)u) << 16); }
__device__ __forceinline__ unsigned short f2bu(float f) {
    bf16 h = __float2bfloat16(f);
    return *reinterpret_cast<unsigned short*>(&h);
}

// async global -> LDS, 16B per lane; LDS dest = uniform base + lane*16
__device__ __forceinline__ void gload_lds16(const void* g, void* l) {
    __builtin_amdgcn_global_load_lds(
        (const __attribute__((address_space(1))) void*)g,
        (__attribute__((address_space(3))) void*)l, 16, 0, 0);
}

// ================= input prep: two convert jobs in one launch =================
__global__ __launch_bounds__(256)
void convert_a2_kernel(const float* __restrict__ A0, bf16* __restrict__ O0,
                       int K0, int Kp0, int t0, int nb0,
                       const float* __restrict__ A1, bf16* __restrict__ O1,
                       int K1, int Kp1, int t1)
{
    if ((int)blockIdx.x < nb0) {
        int idx = blockIdx.x * 256 + threadIdx.x;
        if (idx >= t0) return;
        int r = idx / Kp0, k = idx - r * Kp0;
        O0[idx] = __float2bfloat16((k < K0) ? A0[(size_t)r * K0 + k] : 0.f);
    } else {
        int idx = (blockIdx.x - nb0) * 256 + threadIdx.x;
        if (idx >= t1) return;
        int r = idx / Kp1, k = idx - r * Kp1;
        O1[idx] = __float2bfloat16((k < K1) ? A1[(size_t)r * K1 + k] : 0.f);
    }
}

// all weight transposes in one launch; NW is always 256
struct WtJob  { const float* W; bf16* Wt; int K; int n0; int Kpad; };
struct WtJobs { WtJob j[8]; };
__global__ __launch_bounds__(256)
void convert_wt8_kernel(WtJobs jobs)
{
    WtJob jb = jobs.j[blockIdx.y];
    int n = blockIdx.x;
    for (int k = threadIdx.x; k < jb.Kpad; k += 256) {
        float f = (k < jb.K) ? jb.W[(size_t)k * 256 + n] : 0.f;
        jb.Wt[(size_t)(jb.n0 + n) * jb.Kpad + k] = __float2bfloat16(f);
    }
}

__global__ __launch_bounds__(256)
void concat3_kernel(const float* __restrict__ a, const float* __restrict__ b,
                    const float* __restrict__ c, float* __restrict__ out)
{
    int i = blockIdx.x * 256 + threadIdx.x;
    if (i < 256)      out[i] = a[i];
    else if (i < 512) out[i] = b[i - 256];
    else if (i < 768) out[i] = c[i - 512];
}

// ================= MFMA GEMM (two independent jobs per launch) ================
// r16-proven core: 128x128 tile, BK=64, 4 waves (2x2), 32KB LDS, single-buffer
// global_load_lds, XCD-aware bijective block swizzle over the WHOLE grid.
// Job select on swizzled wgid: wgid < jA.nwg -> job A, else job B.
// JOB A SHOULD BE THE LONG-RUNNING SMALL JOB: wgid 0..nA-1 map back to block
// ids 0,8,16,... (the first dispatch wavefront) so its blocks start at t=0 and
// overlap job B's many rounds instead of forming a serial tail (r17 lesson).
// Plane-split output: slab [ntile*128,+128) -> plane (ntile>>1),
// col (ntile&1)*128+..., base C + (ntile>>1)*PS, row stride 256.
// Runtime act: 0 none, 1 tanh, 2 relu. out_f32: fp32 scalar epilogue (+res).
struct GemmJob {
    const bf16* A; const bf16* Wt; const float* bias; const bf16* res;
    char* C; size_t PS; int M, K, NTILES, nwg, act, out_f32;
};
__global__ __launch_bounds__(256)
void mfma_gemm2_kernel(GemmJob jA, GemmJob jB, int nwgTot)
{
    __shared__ alignas(16) short As[128 * 64];   // 16 KB
    __shared__ alignas(16) short Bs[128 * 64];   // 16 KB

    // bijective XCD swizzle over the whole grid
    const int id  = blockIdx.x;
    const int qq  = nwgTot >> 3, rr = nwgTot & 7;
    const int xcd = id & 7, loc = id >> 3;
    int wgid = (xcd < rr ? xcd * (qq + 1) : rr * (qq + 1) + (xcd - rr) * qq) + loc;

    GemmJob J = (wgid < jA.nwg) ? jA : jB;
    if (wgid >= jA.nwg) wgid -= jA.nwg;
    const int ntile = wgid % J.NTILES, mtile = wgid / J.NTILES;
    const int M = J.M, K = J.K;

    const int tid = threadIdx.x;
    const int lane = tid & 63, wid = tid >> 6;
    const int wr = wid >> 1, wc = wid & 1;

    f32x4 acc[4][4] = {};

    for (int k0 = 0; k0 < K; k0 += 64) {
        #pragma unroll
        for (int i = 0; i < 4; ++i) {
            const int chunk = i * 4 + wid;            // wave-uniform
            const int row   = chunk * 8 + (lane >> 3);
            const int e     = ((lane & 7) ^ (row & 7)) << 3;
            if (mtile * 128 + chunk * 8 + 8 <= M)     // wave-uniform guard (M%8==0)
                gload_lds16(J.A + (size_t)(mtile * 128 + row) * K + k0 + e,
                            &As[chunk * 512]);
            gload_lds16(J.Wt + (size_t)(ntile * 128 + row) * K + k0 + e,
                        &Bs[chunk * 512]);
        }
        __syncthreads();   // drains vmcnt(0): LDS tiles ready
        #pragma unroll
        for (int kk = 0; kk < 2; ++kk) {
            const int coff = (kk * 32 + (lane >> 4) * 8) ^ ((lane & 7) << 3);
            short8 a[4], b[4];
            #pragma unroll
            for (int m = 0; m < 4; ++m)
                a[m] = *reinterpret_cast<const short8*>(
                    &As[(wr * 64 + m * 16 + (lane & 15)) * 64 + coff]);
            #pragma unroll
            for (int n = 0; n < 4; ++n)
                b[n] = *reinterpret_cast<const short8*>(
                    &Bs[(wc * 64 + n * 16 + (lane & 15)) * 64 + coff]);
            #pragma unroll
            for (int m = 0; m < 4; ++m)
                #pragma unroll
                for (int n = 0; n < 4; ++n)
                    acc[m][n] = __builtin_amdgcn_mfma_f32_16x16x32_bf16(
                        a[m], b[n], acc[m][n], 0, 0, 0);
        }
        __syncthreads();
    }

    // epilogue: C/D layout col=lane&15, row=(lane>>4)*4+reg
    const int colbase = (ntile & 1) * 128;
    if (!J.out_f32) {
        bf16* Cp = (bf16*)J.C + (size_t)(ntile >> 1) * J.PS;
        short* eb = (wid < 2 ? As : Bs) + (wid & 1) * 4096;   // wave-private 8KB
        #pragma unroll
        for (int m = 0; m < 4; ++m)
            #pragma unroll
            for (int n = 0; n < 4; ++n) {
                int col_l = n * 16 + (lane & 15);
                float bcol = J.bias[ntile * 128 + wc * 64 + col_l];
                #pragma unroll
                for (int r = 0; r < 4; ++r) {
                    int row_l = m * 16 + ((lane >> 4) << 2) + r;
                    float val = acc[m][n][r] + bcol;
                    if (J.act == 1) val = tanhf(val);
                    if (J.act == 2) val = fmaxf(val, 0.f);
                    eb[row_l * 64 + (col_l ^ ((row_l & 7) << 3))] = (short)f2bu(val);
                }
            }
        #pragma unroll
        for (int i = 0; i < 8; ++i) {
            int row_l = i * 8 + (lane >> 3);
            int row_g = mtile * 128 + wr * 64 + row_l;
            short8 vr = *reinterpret_cast<const short8*>(
                &eb[row_l * 64 + ((((lane & 7) << 3)) ^ ((row_l & 7) << 3))]);
            if (row_g < M)
                *reinterpret_cast<short8*>(
                    &Cp[(size_t)row_g * 256 + colbase + wc * 64 + ((lane & 7) << 3)]) = vr;
        }
    } else {
        float* Cp = (float*)J.C + (size_t)(ntile >> 1) * J.PS;
        #pragma unroll
        for (int m = 0; m < 4; ++m) {
            int row0 = mtile * 128 + wr * 64 + m * 16 + ((lane >> 4) << 2);
            #pragma unroll
            for (int n = 0; n < 4; ++n) {
                int col_l = wc * 64 + n * 16 + (lane & 15);
                float bcol = J.bias[ntile * 128 + col_l];
                #pragma unroll
                for (int r = 0; r < 4; ++r) {
                    int row = row0 + r;
                    if (row < M) {
                        float val = acc[m][n][r] + bcol;
                        if (J.act == 1) val = tanhf(val);
                        if (J.act == 2) val = fmaxf(val, 0.f);
                        if (J.res) val += ldf(&J.res[(size_t)row * 256 + colbase + col_l]);
                        stf(&Cp[(size_t)row * 256 + colbase + col_l], val);
                    }
                }
            }
        }
    }
}

// ================= CSR build =================
__global__ __launch_bounds__(256)
void hist_kernel(const int* __restrict__ dst, int* __restrict__ deg, int E)
{
    int e = blockIdx.x * 256 + threadIdx.x;
    if (e < E) atomicAdd(&deg[dst[e]], 1);
}

__global__ __launch_bounds__(256)
void scan1_kernel(const int* __restrict__ deg, int* __restrict__ part,
                  int* __restrict__ bsum, int n)
{
    __shared__ int sh[256];
    const int t = threadIdx.x;
    const int b0 = blockIdx.x * 1024;
    int v[4]; int s = 0;
    #pragma unroll
    for (int j = 0; j < 4; ++j) {
        int idx = b0 + t * 4 + j;
        v[j] = (idx < n) ? deg[idx] : 0;
        s += v[j];
    }
    sh[t] = s; __syncthreads();
    for (int off = 1; off < 256; off <<= 1) {
        int x = (t >= off) ? sh[t - off] : 0;
        __syncthreads();
        sh[t] += x;
        __syncthreads();
    }
    if (t == 255) bsum[blockIdx.x] = sh[255];
    int run = sh[t] - s;
    #pragma unroll
    for (int j = 0; j < 4; ++j) {
        int idx = b0 + t * 4 + j;
        if (idx < n) part[idx] = run;
        run += v[j];
    }
}

__global__ __launch_bounds__(256)
void scan2_kernel(const int* __restrict__ bsum, int* __restrict__ bsume, int nb)
{
    __shared__ int sh[256];
    const int t = threadIdx.x;
    int x0 = (t < nb) ? bsum[t] : 0;
    sh[t] = x0; __syncthreads();
    for (int off = 1; off < 256; off <<= 1) {
        int x = (t >= off) ? sh[t - off] : 0;
        __syncthreads();
        sh[t] += x;
        __syncthreads();
    }
    if (t < nb) bsume[t] = sh[t] - x0;
}

__global__ __launch_bounds__(256)
void scan3_kernel(int* __restrict__ rowptr, int* __restrict__ cursor,
                  const int* __restrict__ bsume, int n, int E)
{
    int idx = blockIdx.x * 256 + threadIdx.x;
    if (idx < n) {
        int val = rowptr[idx] + bsume[idx >> 10];
        rowptr[idx] = val;
        cursor[idx] = val;
    }
    if (idx == 0) rowptr[n] = E;
}

__global__ __launch_bounds__(256)
void scatter_kernel(const int* __restrict__ src, const int* __restrict__ dst,
                    int* __restrict__ cursor, int* __restrict__ esrc, int E)
{
    int e = blockIdx.x * 256 + threadIdx.x;
    if (e < E) {
        int slot = atomicAdd(&cursor[dst[e]], 1);
        esrc[slot] = src[e];
    }
}

// ================= fused attention + BN column stats (CSR gather, planes) =====
// Grid-stride (4096 blocks x 4 waves). Lane owns the SAME 4 channels for every
// node -> per-lane register sum/sumsq; LDS cross-wave reduce + atomics into
// stats slice (blockIdx&7). 2-edge unroll + branchy rescale (numerically
// identical to always-rescale).
__global__ __launch_bounds__(256)
void attn_fused_kernel(const int* __restrict__ rowptr, const int* __restrict__ esrc,
                       const bf16* __restrict__ q, const bf16* __restrict__ k,
                       const bf16* __restrict__ v, bf16* __restrict__ out,
                       float* __restrict__ stats, int n)
{
    __shared__ float red[8][256];   // [wid]=sum, [wid+4]=sumsq; 8 KB
    const int lane = threadIdx.x & 63;
    const int wid  = threadIdx.x >> 6;

    float cs0 = 0.f, cs1 = 0.f, cs2 = 0.f, cs3 = 0.f;
    float cq0 = 0.f, cq1 = 0.f, cq2 = 0.f, cq3 = 0.f;

    const int stride = gridDim.x * 4;
    for (int node = blockIdx.x * 4 + wid; node < n; node += stride) {
        int lo = rowptr[node], hi = rowptr[node + 1];

        ushort4 qu = ((const ushort4*)(q + (size_t)node * 256))[lane];
        float q0 = bfu(qu.x), q1 = bfu(qu.y), q2 = bfu(qu.z), q3 = bfu(qu.w);

        float m = -INFINITY, s = 0.f;
        float a0 = 0.f, a1 = 0.f, a2 = 0.f, a3 = 0.f;

        auto upd = [&](float l, ushort4 vu) {
            if (l > m) {
                float sc = __expf(m - l);      // exp(-inf)=0 handles first edge
                a0 *= sc; a1 *= sc; a2 *= sc; a3 *= sc; s *= sc;
                m = l;
            }
            float e = __expf(l - m);
            a0 = fmaf(e, bfu(vu.x), a0);
            a1 = fmaf(e, bfu(vu.y), a1);
            a2 = fmaf(e, bfu(vu.z), a2);
            a3 = fmaf(e, bfu(vu.w), a3);
            s += e;
        };

        int i = lo;
        for (; i + 2 <= hi; i += 2) {
            int sn0 = esrc[i], sn1 = esrc[i + 1];
            ushort4 ku0 = ((const ushort4*)(k + (size_t)sn0 * 256))[lane];
            ushort4 vu0 = ((const ushort4*)(v + (size_t)sn0 * 256))[lane];
            ushort4 ku1 = ((const ushort4*)(k + (size_t)sn1 * 256))[lane];
            ushort4 vu1 = ((const ushort4*)(v + (size_t)sn1 * 256))[lane];
            float p0 = q0 * bfu(ku0.x);
            p0 = fmaf(q1, bfu(ku0.y), p0);
            p0 = fmaf(q2, bfu(ku0.z), p0);
            p0 = fmaf(q3, bfu(ku0.w), p0);
            float p1 = q0 * bfu(ku1.x);
            p1 = fmaf(q1, bfu(ku1.y), p1);
            p1 = fmaf(q2, bfu(ku1.z), p1);
            p1 = fmaf(q3, bfu(ku1.w), p1);
            p0 += __shfl_xor(p0, 1);  p1 += __shfl_xor(p1, 1);
            p0 += __shfl_xor(p0, 2);  p1 += __shfl_xor(p1, 2);
            p0 += __shfl_xor(p0, 4);  p1 += __shfl_xor(p1, 4);
            p0 += __shfl_xor(p0, 8);  p1 += __shfl_xor(p1, 8);
            upd(p0 * 0.125f, vu0);
            upd(p1 * 0.125f, vu1);
        }
        if (i < hi) {
            int sn = esrc[i];
            ushort4 ku = ((const ushort4*)(k + (size_t)sn * 256))[lane];
            ushort4 vu = ((const ushort4*)(v + (size_t)sn * 256))[lane];
            float p = q0 * bfu(ku.x);
            p = fmaf(q1, bfu(ku.y), p);
            p = fmaf(q2, bfu(ku.z), p);
            p = fmaf(q3, bfu(ku.w), p);
            p += __shfl_xor(p, 1);
            p += __shfl_xor(p, 2);
            p += __shfl_xor(p, 4);
            p += __shfl_xor(p, 8);
            upd(p * 0.125f, vu);
        }

        float inv = 1.f / (s + 1e-16f);
        ushort4 o;
        o.x = f2bu(fmaxf(a0 * inv, 0.f));
        o.y = f2bu(fmaxf(a1 * inv, 0.f));
        o.z = f2bu(fmaxf(a2 * inv, 0.f));
        o.w = f2bu(fmaxf(a3 * inv, 0.f));
        ((ushort4*)(out + (size_t)node * 256))[lane] = o;

        float r0 = bfu(o.x), r1 = bfu(o.y), r2 = bfu(o.z), r3 = bfu(o.w);
        cs0 += r0; cq0 += r0 * r0;
        cs1 += r1; cq1 += r1 * r1;
        cs2 += r2; cq2 += r2 * r2;
        cs3 += r3; cq3 += r3 * r3;
    }

    red[wid][lane * 4 + 0] = cs0;  red[wid + 4][lane * 4 + 0] = cq0;
    red[wid][lane * 4 + 1] = cs1;  red[wid + 4][lane * 4 + 1] = cq1;
    red[wid][lane * 4 + 2] = cs2;  red[wid + 4][lane * 4 + 2] = cq2;
    red[wid][lane * 4 + 3] = cs3;  red[wid + 4][lane * 4 + 3] = cq3;
    __syncthreads();
    int t = threadIdx.x;
    float ssum = red[0][t] + red[1][t] + red[2][t] + red[3][t];
    float sqq  = red[4][t] + red[5][t] + red[6][t] + red[7][t];
    float* sl = stats + (size_t)(blockIdx.x & 7) * 512;
    atomicAdd(&sl[t], ssum);
    atomicAdd(&sl[256 + t], sqq);
}

// ---------- per-channel BN stats (compact [M,256]) — cline branch (slice 0) ----
__global__ __launch_bounds__(256)
void col_stats_kernel(const bf16* __restrict__ x, float* __restrict__ stats, int M)
{
    const int c = threadIdx.x;
    const int r0 = blockIdx.x * 64;
    const int r1 = min(r0 + 64, M);
    float ls = 0.f, lq = 0.f;
    for (int r = r0; r < r1; ++r) {
        float val = ldf(&x[(size_t)r * 256 + c]);
        ls += val;
        lq += val * val;
    }
    atomicAdd(&stats[c], ls);
    atomicAdd(&stats[256 + c], lq);
}

// ---------- merged BN fold (two jobs): Wt[n][k] *= scale[k], bias update ------
struct FoldJob {
    bf16* Wt; const float* bin; float* bout; const float* stats;
    const float* g; const float* be; float* s_out; float* t_out; float invM;
};
__global__ __launch_bounds__(256)
void bn_fold2_kernel(FoldJob a, FoldJob b, int nA)
{
    __shared__ float sh[256];
    const bool isA = ((int)blockIdx.x < nA);
    FoldJob J = isA ? a : b;
    const int n = isA ? blockIdx.x : blockIdx.x - nA;
    const int k = threadIdx.x;
    float sum = 0.f, sq = 0.f;
    #pragma unroll
    for (int s = 0; s < 8; ++s) {
        sum += J.stats[s * 512 + k];
        sq  += J.stats[s * 512 + 256 + k];
    }
    float mu  = sum * J.invM;
    float var = sq * J.invM - mu * mu;
    float scale = J.g[k] * rsqrtf(var + 1e-5f);
    float shift = J.be[k] - mu * scale;
    float w = ldf(&J.Wt[(size_t)n * 256 + k]);
    J.Wt[(size_t)n * 256 + k] = __float2bfloat16(w * scale);
    sh[k] = shift * w;
    __syncthreads();
    for (int off = 128; off; off >>= 1) {
        if (k < off) sh[k] += sh[k + off];
        __syncthreads();
    }
    if (k == 0) J.bout[n] = J.bin[n] + sh[0];
    if (J.s_out && n == 0) { J.s_out[k] = scale; J.t_out[k] = shift; }
}

// ---------- fused bn2 + residual + segment-mean pool (sums 8 stats slices) ----
__global__ __launch_bounds__(256)
void pool_bn_kernel(const bf16* __restrict__ a2, const bf16* __restrict__ h1,
                    const int* __restrict__ ibatch, const float* __restrict__ stats,
                    const float* __restrict__ g2, const float* __restrict__ be2,
                    const float* __restrict__ s1, const float* __restrict__ t1,
                    float* __restrict__ out, float invM)
{
    int g = blockIdx.x;
    __shared__ int bounds[2];
    if (threadIdx.x == 0) {
        int lo = 0, hi = N_NODES;
        while (lo < hi) { int mid = (lo + hi) >> 1; if (ibatch[mid] < g) lo = mid + 1; else hi = mid; }
        bounds[0] = lo;
        int lo2 = lo, hi2 = N_NODES;
        while (lo2 < hi2) { int mid = (lo2 + hi2) >> 1; if (ibatch[mid] < g + 1) lo2 = mid + 1; else hi2 = mid; }
        bounds[1] = lo2;
    }
    __syncthreads();
    int lo = bounds[0], hi = bounds[1];
    int c = threadIdx.x;
    float sa = 0.f, sh = 0.f;
    for (int r = lo; r < hi; ++r) {
        sa += ldf(&a2[(size_t)r * 256 + c]);
        sh += ldf(&h1[(size_t)r * 256 + c]);
    }
    float sum = 0.f, sq = 0.f;
    #pragma unroll
    for (int s = 0; s < 8; ++s) {
        sum += stats[s * 512 + c];
        sq  += stats[s * 512 + 256 + c];
    }
    float mu  = sum * invM;
    float var = sq * invM - mu * mu;
    float sc2 = g2[c] * rsqrtf(var + 1e-5f);
    float sh2 = be2[c] - mu * sc2;
    int cnt = hi - lo;
    out[(size_t)g * 256 + c] =
        (cnt > 0) ? (sc2 * sa + s1[c] * sh) / cnt + sh2 + t1[c] : 0.f;
}

extern "C" void kernel_launch(void* const* d_in, const int* in_sizes, int n_in,
                              void* d_out, int out_size, void* d_ws, size_t ws_size,
                              hipStream_t stream)
{
    const float* drug_x  = (const float*)d_in[0];
    const int*   adj     = (const int*)  d_in[1];
    const int*   ibatch  = (const int*)  d_in[2];
    const float* cline_x = (const float*)d_in[3];
    const float* Wq1 = (const float*)d_in[4];  const float* bq1 = (const float*)d_in[5];
    const float* Wk1 = (const float*)d_in[6];  const float* bk1 = (const float*)d_in[7];
    const float* Wv1 = (const float*)d_in[8];  const float* bv1 = (const float*)d_in[9];
    const float* g1  = (const float*)d_in[10]; const float* be1 = (const float*)d_in[11];
    const float* Wq2 = (const float*)d_in[12]; const float* bq2 = (const float*)d_in[13];
    const float* Wk2 = (const float*)d_in[14]; const float* bk2 = (const float*)d_in[15];
    const float* Wv2 = (const float*)d_in[16]; const float* bv2 = (const float*)d_in[17];
    const float* g2  = (const float*)d_in[18]; const float* be2 = (const float*)d_in[19];
    const float* Wc1 = (const float*)d_in[20]; const float* bc1 = (const float*)d_in[21];
    const float* gc  = (const float*)d_in[22]; const float* bec = (const float*)d_in[23];
    const float* Wc2 = (const float*)d_in[24]; const float* bc2 = (const float*)d_in[25];

    const int* srcp = adj;
    const int* dstp = adj + N_EDGES;

    // ---- workspace arena (~214 MB) ----
    char* p = (char*)d_ws;
    auto take = [&p](size_t bytes) {
        char* r = p;
        p += (bytes + 15) & ~(size_t)15;
        return r;
    };
    const size_t PS = (size_t)N_NODES * 256;   // plane stride (elements)
    bf16*  qkv   = (bf16*)take(PS * 3 * sizeof(bf16));   // planes q|k|v; attn2 out in q-plane
    bf16*  h1    = (bf16*)take(PS * sizeof(bf16));       // drug_xb -> attnout1
    bf16*  cline_xb = (bf16*)take((size_t)B_CL * 960 * sizeof(bf16)); // dedicated (runs || drug)
    bf16*  c1b   = (bf16*)take((size_t)B_CL * 256 * sizeof(bf16));    // dedicated
    int*   rowptr= (int*)take((size_t)(N_NODES + 1) * sizeof(int));
    int*   degcur= (int*)take((size_t)N_NODES * sizeof(int));
    int*   bsum  = (int*)take(256 * sizeof(int));
    int*   bsume = (int*)take(256 * sizeof(int));
    int*   esrc  = (int*)take((size_t)N_EDGES * sizeof(int));
    float* stats = (float*)take(8 * 512 * sizeof(float));   // drug BN stats (8 slices)
    float* statsC= (float*)take(8 * 512 * sizeof(float));   // cline BN stats
    float* s1buf = (float*)take(256 * sizeof(float));
    float* t1buf = (float*)take(256 * sizeof(float));
    bf16*  Wt1   = (bf16*)take((size_t)768 * 128 * sizeof(bf16));
    bf16*  Wt2   = (bf16*)take((size_t)768 * 256 * sizeof(bf16));
    bf16*  Wtc1  = (bf16*)take((size_t)256 * 960 * sizeof(bf16));
    bf16*  Wtc2  = (bf16*)take((size_t)256 * 256 * sizeof(bf16));
    float* bc2f  = (float*)take(256 * sizeof(float));
    float* bias1 = (float*)take(768 * sizeof(float));
    float* bias2 = (float*)take(768 * sizeof(float));
    size_t needed = (size_t)(p - (char*)d_ws);
    if (ws_size < needed) return;

    bf16* drug_xb = h1;         // [N,128] bf16, dead before L1 attn writes
    bf16* qpl = qkv;            // q plane
    bf16* kpl = qkv + PS;       // k plane
    bf16* vpl = qkv + 2 * PS;   // v plane

    float* out_pool = (float*)d_out;                      // [G,256]
    float* out_c    = out_pool + (size_t)N_GRAPH * OUT_C; // [B,256]

    const int MT_N = (N_NODES + 127) / 128;  // 782 mtiles
    const int nwgN = 6 * MT_N;               // drug GEMM: 6 ntiles (768/128)
    const int nwgB = 2 * (B_CL / 128);       // 32 (NTILES=2)

    // ===================== prep =====================
    const int nb_drug = (N_NODES * 128 + 255) / 256;
    const int nb_cl   = (B_CL * 960 + 255) / 256;
    convert_a2_kernel<<<nb_drug + nb_cl, 256, 0, stream>>>(
        drug_x, drug_xb, DRUG_DIM, 128, N_NODES * 128, nb_drug,
        cline_x, cline_xb, CLINE_DIM, 960, B_CL * 960);
    WtJobs jobs = {{
        { Wq1, Wt1, DRUG_DIM,   0, 128 },
        { Wk1, Wt1, DRUG_DIM, 256, 128 },
        { Wv1, Wt1, DRUG_DIM, 512, 128 },
        { Wq2, Wt2, 256,        0, 256 },
        { Wk2, Wt2, 256,      256, 256 },
        { Wv2, Wt2, 256,      512, 256 },
        { Wc1, Wtc1, CLINE_DIM, 0, 960 },
        { Wc2, Wtc2, 256,       0, 256 },
    }};
    convert_wt8_kernel<<<dim3(256, 8), 256, 0, stream>>>(jobs);
    concat3_kernel<<<3, 256, 0, stream>>>(bq1, bk1, bv1, bias1);
    concat3_kernel<<<3, 256, 0, stream>>>(bq2, bk2, bv2, bias2);

    // ===================== CSR build =====================
    hipMemsetAsync(degcur, 0, N_NODES * sizeof(int), stream);
    hist_kernel<<<(N_EDGES + 255) / 256, 256, 0, stream>>>(dstp, degcur, N_EDGES);
    const int NB1 = (N_NODES + 1023) / 1024;
    scan1_kernel<<<NB1, 256, 0, stream>>>(degcur, rowptr, bsum, N_NODES);
    scan2_kernel<<<1, 256, 0, stream>>>(bsum, bsume, NB1);
    scan3_kernel<<<(N_NODES + 255) / 256, 256, 0, stream>>>(rowptr, degcur, bsume, N_NODES, N_EDGES);
    scatter_kernel<<<(N_EDGES + 255) / 256, 256, 0, stream>>>(srcp, dstp, degcur, esrc, N_EDGES);
    hipMemsetAsync(stats, 0, 2 * 8 * 512 * sizeof(float), stream);  // stats + statsC

    // ============ layer 1: cline GEMM1 (long, first) || drug qkv GEMM ============
    GemmJob jDrug1 = { drug_xb, Wt1, bias1, nullptr, (char*)qkv, PS,
                       N_NODES, 128, 6, nwgN, 0, 0 };
    GemmJob jCl1   = { cline_xb, Wtc1, bc1, nullptr, (char*)c1b, 0,
                       B_CL, 960, 2, nwgB, 1, 0 };
    mfma_gemm2_kernel<<<nwgN + nwgB, 256, 0, stream>>>(jCl1, jDrug1, nwgN + nwgB);
    // attnout1 (relu'd) -> compact [N,256] into h1 slot, with fused BN1 stats
    attn_fused_kernel<<<4096, 256, 0, stream>>>(rowptr, esrc, qpl, kpl, vpl, h1,
                                                stats, N_NODES);
    // cline BN stats (independent, tiny)
    col_stats_kernel<<<(B_CL + 63) / 64, 256, 0, stream>>>(c1b, statsC, B_CL);
    // merged fold: BN1 -> Wt2/bias2 (+s1/t1) ; clineBN -> Wtc2/bc2f
    FoldJob fDrug = { Wt2, bias2, bias2, stats, g1, be1, s1buf, t1buf, 1.0f / N_NODES };
    FoldJob fCl   = { Wtc2, bc2, bc2f, statsC, gc, bec, nullptr, nullptr, 1.0f / B_CL };
    bn_fold2_kernel<<<768 + 256, 256, 0, stream>>>(fDrug, fCl, 768);

    // ============ layer 2: cline GEMM2 (first) || drug qkv GEMM ============
    GemmJob jDrug2 = { h1, Wt2, bias2, nullptr, (char*)qkv, PS,
                       N_NODES, 256, 6, nwgN, 0, 0 };
    GemmJob jCl2   = { c1b, Wtc2, bc2f, c1b, (char*)out_c, 0,
                       B_CL, 256, 2, nwgB, 2, 1 };
    mfma_gemm2_kernel<<<nwgN + nwgB, 256, 0, stream>>>(jCl2, jDrug2, nwgN + nwgB);
    // attnout2 -> in-place q-plane (compact), with fused BN2 stats
    hipMemsetAsync(stats, 0, 8 * 512 * sizeof(float), stream);
    attn_fused_kernel<<<4096, 256, 0, stream>>>(rowptr, esrc, qpl, kpl, vpl, qpl,
                                                stats, N_NODES);
    // fused: pooled = sc2*mean(attnout2) + s1*mean(attnout1) + sh2 + t1
    pool_bn_kernel<<<N_GRAPH, 256, 0, stream>>>(qpl, h1, ibatch, stats,
                                                g2, be2, s1buf, t1buf, out_pool,
                                                1.0f / N_NODES);
}